// Round 2
// 2135.998 us; speedup vs baseline: 1.8935x; 1.8935x over previous
//
#include <hip/hip_runtime.h>

#define B_ 4
#define C_ 2048
#define N_ 2304   // 48*48
#define D_ 256

typedef _Float16 f16;
typedef __attribute__((ext_vector_type(8))) _Float16 f16x8;
typedef __attribute__((ext_vector_type(4))) float    f32x4;

// ---------------------------------------------------------------------------
// proj: Y[b,n,d] = sum_c X[b,c,n] * W[d,c] + bias[d]   (proven baseline)
// ---------------------------------------------------------------------------
__global__ __launch_bounds__(256) void proj_kernel(
    const float* __restrict__ X, const float* __restrict__ W,
    const float* __restrict__ bias, float* __restrict__ Y)
{
    const int b  = blockIdx.z;
    const int n0 = blockIdx.x * 64;
    const int d0 = blockIdx.y * 64;
    const int tid = threadIdx.x;
    const int tx = tid & 15, ty = tid >> 4;

    __shared__ float Xs[16][68];
    __shared__ float Ws[16][68];

    float acc[4][4] = {};

    for (int c0 = 0; c0 < C_; c0 += 16) {
        {
            const int k  = tid >> 4;
            const int nq = (tid & 15) << 2;
            const float4 v = *(const float4*)&X[((size_t)b*C_ + (c0+k))*N_ + n0 + nq];
            *(float4*)&Xs[k][nq] = v;
        }
        {
            const int d  = tid >> 2;
            const int kq = (tid & 3) << 2;
            const float4 v = *(const float4*)&W[(size_t)(d0+d)*C_ + c0 + kq];
            Ws[kq+0][d] = v.x; Ws[kq+1][d] = v.y; Ws[kq+2][d] = v.z; Ws[kq+3][d] = v.w;
        }
        __syncthreads();
        #pragma unroll
        for (int k = 0; k < 16; ++k) {
            const float4 a = *(const float4*)&Xs[k][ty << 2];
            const float4 w = *(const float4*)&Ws[k][tx << 2];
            const float av[4] = {a.x, a.y, a.z, a.w};
            const float wv[4] = {w.x, w.y, w.z, w.w};
            #pragma unroll
            for (int i = 0; i < 4; ++i)
                #pragma unroll
                for (int j = 0; j < 4; ++j)
                    acc[i][j] += av[i] * wv[j];
        }
        __syncthreads();
    }

    const float4 bb = *(const float4*)&bias[d0 + (tx << 2)];
    #pragma unroll
    for (int i = 0; i < 4; ++i) {
        float4 o;
        o.x = acc[i][0] + bb.x; o.y = acc[i][1] + bb.y;
        o.z = acc[i][2] + bb.z; o.w = acc[i][3] + bb.w;
        *(float4*)&Y[((size_t)b*N_ + n0 + (ty<<2) + i)*D_ + d0 + (tx<<2)] = o;
    }
}

// ---------------------------------------------------------------------------
// scores: S[n,m] = sum_d Q[b,n,d] * K[b,m,d]   (proven baseline; S = row base)
// ---------------------------------------------------------------------------
__global__ __launch_bounds__(256) void scores_kernel(
    const float* __restrict__ Q, const float* __restrict__ K,
    float* __restrict__ S, int b)
{
    const int n0 = blockIdx.x * 64;
    const int m0 = blockIdx.y * 64;
    const int tid = threadIdx.x;
    const int tx = tid & 15, ty = tid >> 4;

    __shared__ float Qs[16][68];
    __shared__ float Ks[16][68];

    float acc[4][4] = {};

    for (int d0 = 0; d0 < D_; d0 += 16) {
        {
            const int r  = tid >> 2;
            const int kq = (tid & 3) << 2;
            const float4 v = *(const float4*)&Q[((size_t)b*N_ + n0 + r)*D_ + d0 + kq];
            Qs[kq+0][r] = v.x; Qs[kq+1][r] = v.y; Qs[kq+2][r] = v.z; Qs[kq+3][r] = v.w;
            const float4 u = *(const float4*)&K[((size_t)b*N_ + m0 + r)*D_ + d0 + kq];
            Ks[kq+0][r] = u.x; Ks[kq+1][r] = u.y; Ks[kq+2][r] = u.z; Ks[kq+3][r] = u.w;
        }
        __syncthreads();
        #pragma unroll
        for (int k = 0; k < 16; ++k) {
            const float4 a = *(const float4*)&Qs[k][ty << 2];
            const float4 w = *(const float4*)&Ks[k][tx << 2];
            const float av[4] = {a.x, a.y, a.z, a.w};
            const float wv[4] = {w.x, w.y, w.z, w.w};
            #pragma unroll
            for (int i = 0; i < 4; ++i)
                #pragma unroll
                for (int j = 0; j < 4; ++j)
                    acc[i][j] += av[i] * wv[j];
        }
        __syncthreads();
    }

    #pragma unroll
    for (int i = 0; i < 4; ++i) {
        float4 o; o.x = acc[i][0]; o.y = acc[i][1]; o.z = acc[i][2]; o.w = acc[i][3];
        *(float4*)&S[(size_t)(n0 + (ty<<2) + i)*N_ + m0 + (tx<<2)] = o;
    }
}

// ---------------------------------------------------------------------------
// softmax over rows of S; single global read (row in regs), emits P split-f16
// IN PLACE: row bytes [0,2N) = P_hi, [2N,4N) = P_lo,  P ≈ hi + lo
// ---------------------------------------------------------------------------
__global__ __launch_bounds__(256) void softmax_kernel(float* __restrict__ S)
{
    float* row = S + (size_t)blockIdx.x * N_;
    const int tid = threadIdx.x;
    __shared__ float red[256];

    float v[9];
    float m = -3.4e38f;
    #pragma unroll
    for (int k = 0; k < 9; ++k) { v[k] = row[tid + k*256]; m = fmaxf(m, v[k]); }
    red[tid] = m; __syncthreads();
    for (int s = 128; s > 0; s >>= 1) {
        if (tid < s) red[tid] = fmaxf(red[tid], red[tid + s]);
        __syncthreads();
    }
    m = red[0]; __syncthreads();

    float sum = 0.f;
    #pragma unroll
    for (int k = 0; k < 9; ++k) { v[k] = __expf(v[k] - m); sum += v[k]; }
    red[tid] = sum; __syncthreads();
    for (int s = 128; s > 0; s >>= 1) {
        if (tid < s) red[tid] += red[tid + s];
        __syncthreads();
    }
    const float inv = 1.0f / red[0];

    f16* rowh = (f16*)row;
    #pragma unroll
    for (int k = 0; k < 9; ++k) {
        const float p = v[k] * inv;
        const f16 hi = (f16)p;
        const f16 lo = (f16)(p - (float)hi);
        rowh[tid + k*256]      = hi;
        rowh[N_ + tid + k*256] = lo;
    }
}

// ---------------------------------------------------------------------------
// out (MFMA): O[b, C+c, n] = sum_m P[b,n,m] * V[b,c,m], split-f16 3-term:
//   O ≈ Vhi*Phi + Vhi*Plo + Vlo*Phi     (≈2^-22 relative error)
// Covers `grid/288` batches starting at b_off (1152 fused, 288 fallback).
// Block tile 128(c) x 128(n) x BK=32(m); 4 waves 2x2; wave tile 64x64 as 4x4
// fragments of mfma_f32_16x16x32_f16.
// LDS: 2 bufs x 4 tiles {Vhi,Vlo,Phi,Plo} x [128 rows][32 m] f16 = 64 KiB.
// P tiles staged via global_load_lds from the in-place hi/lo f16 rows of S;
// V tiles reg-staged from fp32 and split in-register (T14 issue-early /
// write-late). Chunk-XOR swizzle c' = c ^ ((row>>1)&3), applied identically
// on the stage side and the ds_read side (involution).
// Operand layout (16x16x32): lane row/col = l&15, k = 8*(l>>4)+e;
// C/D: col = l&15, row = (l>>4)*4 + reg (m89-verified, dtype-independent).
// ---------------------------------------------------------------------------
__global__ __launch_bounds__(256, 2) void out_mfma_kernel(
    const float* __restrict__ Sall, const float* __restrict__ V,
    float* __restrict__ O, int b_off)
{
    __shared__ __align__(16) char smem[2][4][8192];
    char* const smbase = &smem[0][0][0];

    const int tid = threadIdx.x;
    const int w = tid >> 6;            // wave 0..3
    const int l = tid & 63;

    // XCD-chunked swizzle (grid % 8 == 0)
    const int chunks = gridDim.x >> 3;
    const int bid = blockIdx.x;
    const int lin = (bid & 7) * chunks + (bid >> 3);
    const int bl  = lin / 288;         // local batch within this dispatch
    const int rr  = lin - bl * 288;
    const int cb  = rr / 18;           // c-tile (outer)
    const int nb  = rr - cb * 18;      // n-tile (inner: consecutive share V panel)
    const int b   = b_off + bl;
    const int c0 = cb * 128, n0 = nb * 128;

    // ---- P staging setup: wave w stages q = 2w, 2w+1 of both Phi and Plo ---
    // gload_lds lane layout: LDS off q*1024 + l*16 -> row=q*16+(l>>2), c'=l&3
    // logical chunk to fetch = (l&3) ^ ((row>>1)&3) = (l&3) ^ ((l>>3)&3)
    const int srow4  = l >> 2;
    const int schunk = (l & 3) ^ ((l >> 3) & 3);
    const char* Sb  = (const char*)Sall + (size_t)bl * N_ * N_ * 4;
    const char* gP0 = Sb + (size_t)(n0 + 2*w*16 + srow4) * ((size_t)N_ * 4) + schunk * 16;
    const char* gP1 = gP0 + (size_t)16 * N_ * 4;

    // ---- V staging setup: thread handles row vr, logical chunks vc, vc+1 ---
    const int vr = tid >> 1;                 // 0..127
    const int vc = (tid & 1) << 1;           // 0 or 2 (chunks of 8 elems)
    const float* Vg = V + ((size_t)b * C_ + c0 + vr) * N_ + (vc << 3);
    const int vswz = (vr >> 1) & 3;
    const int wV0 = vr * 64 + ((vc    ) ^ vswz) * 16;   // byte off in Vhi tile
    const int wV1 = vr * 64 + ((vc + 1) ^ vswz) * 16;

    // ---- fragment-read offsets (row = quad*64 + f*16 + (l&15)) -------------
    const int wr = w >> 1, wc = w & 1;
    const int rc   = ((l >> 4) ^ ((l >> 1) & 3)) << 4;
    const int offA = (wr * 64 + (l & 15)) * 64 + rc;    // V tiles (rows = c)
    const int offB = (wc * 64 + (l & 15)) * 64 + rc;    // P tiles (rows = n)

    f32x4 acc[4][4] = {};

    #define GLL(gp, dp)                                                        \
        __builtin_amdgcn_global_load_lds(                                      \
            (const __attribute__((address_space(1))) void*)(gp),               \
            (__attribute__((address_space(3))) void*)(dp), 16, 0, 0)

    #define STAGEP(buf, s)                                                     \
        {                                                                      \
            const char* g0_ = gP0 + (size_t)(s) * 64;                          \
            const char* g1_ = gP1 + (size_t)(s) * 64;                          \
            char* dh_ = smbase + (buf) * 32768 + 16384 + 2 * w * 1024;         \
            char* dl_ = dh_ + 8192;                                            \
            GLL(g0_, dh_);           GLL(g0_ + 4608, dl_);                     \
            GLL(g1_, dh_ + 1024);    GLL(g1_ + 4608, dl_ + 1024);              \
        }

    #define VLOAD(s, x0, x1, x2, x3)                                           \
        {                                                                      \
            const float* vg_ = Vg + (size_t)(s) * 32;                          \
            x0 = *(const float4*)(vg_ + 0);  x1 = *(const float4*)(vg_ + 4);   \
            x2 = *(const float4*)(vg_ + 8);  x3 = *(const float4*)(vg_ + 12);  \
        }

    #define CVT8(a, c, hi, lo)                                                 \
        {                                                                      \
            const float xs_[8] = {a.x, a.y, a.z, a.w, c.x, c.y, c.z, c.w};     \
            _Pragma("unroll")                                                  \
            for (int i_ = 0; i_ < 8; ++i_) {                                   \
                const f16 h_ = (f16)xs_[i_];                                   \
                hi[i_] = h_; lo[i_] = (f16)(xs_[i_] - (float)h_);              \
            }                                                                  \
        }

    #define VWRITE(buf, x0, x1, x2, x3)                                        \
        {                                                                      \
            f16x8 h0_, l0_, h1_, l1_;                                          \
            CVT8(x0, x1, h0_, l0_); CVT8(x2, x3, h1_, l1_);                    \
            char* bb_ = smbase + (buf) * 32768;                                \
            *(f16x8*)(bb_ + wV0)        = h0_;                                 \
            *(f16x8*)(bb_ + 8192 + wV0) = l0_;                                 \
            *(f16x8*)(bb_ + wV1)        = h1_;                                 \
            *(f16x8*)(bb_ + 8192 + wV1) = l1_;                                 \
        }

    // prologue: stage tile 0 into buffer 0
    {
        float4 xa, xb, xc, xd;
        VLOAD(0, xa, xb, xc, xd);
        STAGEP(0, 0);
        VWRITE(0, xa, xb, xc, xd);
    }
    __syncthreads();

    const int NSTEP = N_ / 32;   // 72
    for (int s = 0; s < NSTEP; ++s) {
        const int cur = s & 1;
        const bool more = (s + 1 < NSTEP);
        float4 xa, xb, xc, xd;
        if (more) {
            VLOAD(s + 1, xa, xb, xc, xd);      // issue early (hide HBM latency)
            STAGEP(cur ^ 1, s + 1);            // async P prefetch
        }

        const char* t = smbase + cur * 32768;
        f16x8 va0[4], va1[4], pb0[4], pb1[4];
        #pragma unroll
        for (int f = 0; f < 4; ++f) {
            va0[f] = *(const f16x8*)(t +         offA + f * 1024);
            va1[f] = *(const f16x8*)(t +  8192 + offA + f * 1024);
            pb0[f] = *(const f16x8*)(t + 16384 + offB + f * 1024);
            pb1[f] = *(const f16x8*)(t + 24576 + offB + f * 1024);
        }
        #pragma unroll
        for (int i = 0; i < 4; ++i)
            #pragma unroll
            for (int j = 0; j < 4; ++j) {
                acc[i][j] = __builtin_amdgcn_mfma_f32_16x16x32_f16(va0[i], pb0[j], acc[i][j], 0, 0, 0);
                acc[i][j] = __builtin_amdgcn_mfma_f32_16x16x32_f16(va0[i], pb1[j], acc[i][j], 0, 0, 0);
                acc[i][j] = __builtin_amdgcn_mfma_f32_16x16x32_f16(va1[i], pb0[j], acc[i][j], 0, 0, 0);
            }

        if (more) VWRITE(cur ^ 1, xa, xb, xc, xd);   // write late
        __syncthreads();
    }
    #undef GLL
    #undef STAGEP
    #undef VLOAD
    #undef CVT8
    #undef VWRITE

    // ---- epilogue: D col = l&15 (n), row = (l>>4)*4 + reg (c) --------------
    float* Ob = O + ((size_t)b * (2 * C_) + C_) * N_;
    const int orow = c0 + wr * 64 + ((l >> 4) << 2);
    const int ocol = n0 + wc * 64 + (l & 15);
    #pragma unroll
    for (int i = 0; i < 4; ++i)
        #pragma unroll
        for (int j = 0; j < 4; ++j)
            #pragma unroll
            for (int p = 0; p < 4; ++p)
                Ob[(size_t)(orow + i * 16 + p) * N_ + (ocol + j * 16)] = acc[i][j][p];
}

// ---------------------------------------------------------------------------
// copy pass-through features X [B,C,N] -> O[b, 0..C, n] where O is [B,2C,N]
// ---------------------------------------------------------------------------
__global__ __launch_bounds__(256) void copy_kernel(
    const float4* __restrict__ X, float4* __restrict__ O)
{
    const size_t perb = (size_t)C_ * N_ / 4;
    const size_t i = (size_t)blockIdx.x * 256 + threadIdx.x;
    const size_t b = i / perb, r = i - b * perb;
    O[b * 2 * perb + r] = X[i];
}

extern "C" void kernel_launch(void* const* d_in, const int* in_sizes, int n_in,
                              void* d_out, int out_size, void* d_ws, size_t ws_size,
                              hipStream_t stream)
{
    const float* left  = (const float*)d_in[0];
    const float* right = (const float*)d_in[1];
    const float* wq    = (const float*)d_in[2];
    const float* bq    = (const float*)d_in[3];
    const float* wr    = (const float*)d_in[4];
    const float* br    = (const float*)d_in[5];
    float* out = (float*)d_out;
    float* ws  = (float*)d_ws;

    const size_t QKn = (size_t)B_ * N_ * D_;        // 2,359,296 floats
    const size_t NN  = (size_t)N_ * N_;             // 5,308,416 floats

    float* Q  = ws;
    float* Kp = Q + QKn;
    float* S  = Kp + QKn;

    // fused (4-batch S_all, 103.8 MB) if workspace allows, else baseline
    // footprint (per-batch S, 40.1 MB — proven budget)
    const bool fused = ws_size >= (2 * QKn + 4 * NN) * sizeof(float);

    float* out1 = out;
    float* out2 = out + (size_t)B_ * 2 * C_ * N_;

    const dim3 blk(256);
    const dim3 gproj(N_/64, D_/64, B_);
    const dim3 gsc(N_/64, N_/64);
    const int  gcopy = (B_ * C_ * N_ / 4) / 256;    // 18432

    copy_kernel<<<gcopy, blk, 0, stream>>>((const float4*)left,  (float4*)out1);
    copy_kernel<<<gcopy, blk, 0, stream>>>((const float4*)right, (float4*)out2);

    // ---- co-attend 1: query=left, ref=right -> weighted_r in out1[C,2C) ----
    proj_kernel<<<gproj, blk, 0, stream>>>(left,  wq, bq, Q);
    proj_kernel<<<gproj, blk, 0, stream>>>(right, wr, br, Kp);
    if (fused) {
        for (int b = 0; b < B_; ++b) {
            scores_kernel<<<gsc, blk, 0, stream>>>(Q, Kp, S + (size_t)b * NN, b);
            softmax_kernel<<<N_, blk, 0, stream>>>(S + (size_t)b * NN);
        }
        out_mfma_kernel<<<dim3(1152), blk, 0, stream>>>(S, right, out1, 0);
    } else {
        for (int b = 0; b < B_; ++b) {
            scores_kernel<<<gsc, blk, 0, stream>>>(Q, Kp, S, b);
            softmax_kernel<<<N_, blk, 0, stream>>>(S);
            out_mfma_kernel<<<dim3(288), blk, 0, stream>>>(S, right, out1, b);
        }
    }

    // ---- co-attend 2: query=right, ref=left -> weighted_l in out2[C,2C) ----
    proj_kernel<<<gproj, blk, 0, stream>>>(right, wq, bq, Q);
    proj_kernel<<<gproj, blk, 0, stream>>>(left,  wr, br, Kp);
    if (fused) {
        for (int b = 0; b < B_; ++b) {
            scores_kernel<<<gsc, blk, 0, stream>>>(Q, Kp, S + (size_t)b * NN, b);
            softmax_kernel<<<N_, blk, 0, stream>>>(S + (size_t)b * NN);
        }
        out_mfma_kernel<<<dim3(1152), blk, 0, stream>>>(S, left, out2, 0);
    } else {
        for (int b = 0; b < B_; ++b) {
            scores_kernel<<<gsc, blk, 0, stream>>>(Q, Kp, S, b);
            softmax_kernel<<<N_, blk, 0, stream>>>(S);
            out_mfma_kernel<<<dim3(288), blk, 0, stream>>>(S, left, out2, b);
        }
    }
}

// Round 3
// 1537.874 us; speedup vs baseline: 2.6300x; 1.3889x over previous
//
#include <hip/hip_runtime.h>

#define B_ 4
#define C_ 2048
#define N_ 2304   // 48*48
#define D_ 256

typedef _Float16 f16;
typedef __attribute__((ext_vector_type(8))) _Float16 f16x8;
typedef __attribute__((ext_vector_type(4))) _Float16 f16x4;
typedef __attribute__((ext_vector_type(4))) float    f32x4;

#define GLL(gp, dp)                                                        \
    __builtin_amdgcn_global_load_lds(                                      \
        (const __attribute__((address_space(1))) void*)(gp),               \
        (__attribute__((address_space(3))) void*)(dp), 16, 0, 0)

// ---------------------------------------------------------------------------
// proj (fp32 VALU core, split-f16 epilogue):
//   z<4 : batch z,  Y = Q = X_q · wq^T + bq
//   z>=4: batch z-4, Y = K = X_r · wr^T + br
// emits Yhi[b,n,d], Ylo[b,n,d] (f16) with Y ≈ hi + lo (22-bit mantissa)
// ---------------------------------------------------------------------------
__global__ __launch_bounds__(256) void proj_kernel(
    const float* __restrict__ Xq, const float* __restrict__ Xr,
    const float* __restrict__ wq, const float* __restrict__ bq,
    const float* __restrict__ wr, const float* __restrict__ br,
    f16* __restrict__ Qh, f16* __restrict__ Kh)
{
    const size_t NQ = (size_t)B_ * N_ * D_;
    const int z  = blockIdx.z;
    const int b  = z & 3;
    const float* X; const float* W; const float* bias; f16* Y;
    if (z < 4) { X = Xq; W = wq; bias = bq; Y = Qh; }
    else       { X = Xr; W = wr; bias = br; Y = Kh; }
    f16* Yl = Y + NQ;

    const int n0 = blockIdx.x * 64;
    const int d0 = blockIdx.y * 64;
    const int tid = threadIdx.x;
    const int tx = tid & 15, ty = tid >> 4;

    __shared__ float Xs[16][68];
    __shared__ float Ws[16][68];

    float acc[4][4] = {};

    for (int c0 = 0; c0 < C_; c0 += 16) {
        {
            const int k  = tid >> 4;
            const int nq = (tid & 15) << 2;
            const float4 v = *(const float4*)&X[((size_t)b*C_ + (c0+k))*N_ + n0 + nq];
            *(float4*)&Xs[k][nq] = v;
        }
        {
            const int d  = tid >> 2;
            const int kq = (tid & 3) << 2;
            const float4 v = *(const float4*)&W[(size_t)(d0+d)*C_ + c0 + kq];
            Ws[kq+0][d] = v.x; Ws[kq+1][d] = v.y; Ws[kq+2][d] = v.z; Ws[kq+3][d] = v.w;
        }
        __syncthreads();
        #pragma unroll
        for (int k = 0; k < 16; ++k) {
            const float4 a = *(const float4*)&Xs[k][ty << 2];
            const float4 w = *(const float4*)&Ws[k][tx << 2];
            const float av[4] = {a.x, a.y, a.z, a.w};
            const float wv[4] = {w.x, w.y, w.z, w.w};
            #pragma unroll
            for (int i = 0; i < 4; ++i)
                #pragma unroll
                for (int j = 0; j < 4; ++j)
                    acc[i][j] += av[i] * wv[j];
        }
        __syncthreads();
    }

    const float4 bb = *(const float4*)&bias[d0 + (tx << 2)];
    #pragma unroll
    for (int i = 0; i < 4; ++i) {
        float o[4];
        o[0] = acc[i][0] + bb.x; o[1] = acc[i][1] + bb.y;
        o[2] = acc[i][2] + bb.z; o[3] = acc[i][3] + bb.w;
        f16x4 h, lo;
        #pragma unroll
        for (int j = 0; j < 4; ++j) {
            const f16 hh = (f16)o[j];
            h[j] = hh; lo[j] = (f16)(o[j] - (float)hh);
        }
        const size_t idx = ((size_t)b*N_ + n0 + (ty<<2) + i)*D_ + d0 + (tx<<2);
        *(f16x4*)&Y[idx]  = h;
        *(f16x4*)&Yl[idx] = lo;
    }
}

// ---------------------------------------------------------------------------
// scores (MFMA): S[bl,n,m] = sum_d Q[bl,n,d]*K[bl,m,d], split-f16 3-term
//   (QhiKhi + QhiKlo + QloKhi).  One dispatch = all 4 batches, 1296 blocks.
// Block 128(n) x 128(m) x 32(d); 4 waves 2x2; all 4 tiles staged via
// global_load_lds with the chunk-XOR involution (c' = c ^ ((row>>1)&3)).
// ---------------------------------------------------------------------------
__global__ __launch_bounds__(256, 2) void scores_mfma_kernel(
    const f16* __restrict__ Qh, const f16* __restrict__ Kh,
    float* __restrict__ Sall)
{
    __shared__ __align__(16) char smem[2][4][8192];
    char* const smbase = &smem[0][0][0];

    const int tid = threadIdx.x;
    const int w = tid >> 6, l = tid & 63;

    const int chunks = gridDim.x >> 3;     // 162
    const int bid = blockIdx.x;
    const int lin = (bid & 7) * chunks + (bid >> 3);
    const int bl = lin / 324;
    const int rr = lin - bl * 324;
    const int mb = rr / 18;                // m-tile outer (K panel reused)
    const int nb = rr - mb * 18;           // n inner
    const int n0 = nb * 128, m0 = mb * 128;

    // wave w stages tile w: 0=Qhi 1=Qlo 2=Khi 3=Klo  (8 gloads, q=0..7)
    const size_t NQ = (size_t)B_ * N_ * D_;
    const int srow   = l >> 2;
    const int schunk = (l & 3) ^ ((l >> 3) & 3);
    const f16* tp = (w & 2) ? Kh : Qh;
    if (w & 1) tp += NQ;
    const int rbase = (w & 2) ? m0 : n0;
    const char* gT = (const char*)(tp + ((size_t)bl*N_ + rbase + srow)*D_) + schunk*16;
    const size_t rstep = (size_t)16 * D_ * 2;

    const int wr = w >> 1, wc = w & 1;
    const int rc   = ((l >> 4) ^ ((l >> 1) & 3)) << 4;
    const int offA = (wr * 64 + (l & 15)) * 64 + rc;   // Q rows (n)
    const int offB = (wc * 64 + (l & 15)) * 64 + rc;   // K rows (m)

    f32x4 acc[4][4] = {};

    #define STAGES(buf, s)                                                 \
        {                                                                  \
            const char* g_ = gT + (size_t)(s) * 64;                        \
            char* d_ = smbase + (buf) * 32768 + w * 8192;                  \
            _Pragma("unroll")                                              \
            for (int q = 0; q < 8; ++q) GLL(g_ + q*rstep, d_ + q*1024);    \
        }

    STAGES(0, 0);
    __syncthreads();

    const int NSTEP = D_ / 32;   // 8
    for (int s = 0; s < NSTEP; ++s) {
        const int cur = s & 1;
        if (s + 1 < NSTEP) STAGES(cur ^ 1, s + 1);

        const char* t = smbase + cur * 32768;
        f16x8 qa0[4], qa1[4], kb0[4], kb1[4];
        #pragma unroll
        for (int f = 0; f < 4; ++f) {
            qa0[f] = *(const f16x8*)(t +         offA + f * 1024);
            qa1[f] = *(const f16x8*)(t +  8192 + offA + f * 1024);
            kb0[f] = *(const f16x8*)(t + 16384 + offB + f * 1024);
            kb1[f] = *(const f16x8*)(t + 24576 + offB + f * 1024);
        }
        #pragma unroll
        for (int i = 0; i < 4; ++i)
            #pragma unroll
            for (int j = 0; j < 4; ++j) {
                acc[i][j] = __builtin_amdgcn_mfma_f32_16x16x32_f16(qa0[i], kb0[j], acc[i][j], 0, 0, 0);
                acc[i][j] = __builtin_amdgcn_mfma_f32_16x16x32_f16(qa0[i], kb1[j], acc[i][j], 0, 0, 0);
                acc[i][j] = __builtin_amdgcn_mfma_f32_16x16x32_f16(qa1[i], kb0[j], acc[i][j], 0, 0, 0);
            }
        __syncthreads();
    }
    #undef STAGES

    float* Sb = Sall + (size_t)bl * N_ * N_;
    const int orow = n0 + wr * 64 + ((l >> 4) << 2);
    const int ocol = m0 + wc * 64 + (l & 15);
    #pragma unroll
    for (int i = 0; i < 4; ++i)
        #pragma unroll
        for (int j = 0; j < 4; ++j)
            #pragma unroll
            for (int p = 0; p < 4; ++p)
                Sb[(size_t)(orow + i*16 + p) * N_ + (ocol + j*16)] = acc[i][j][p];
}

// ---------------------------------------------------------------------------
// softmax over rows of S (4 batches contiguous, grid = 4*N_); emits split-f16
// P in place: row bytes [0,2N) = P_hi, [2N,4N) = P_lo
// ---------------------------------------------------------------------------
__global__ __launch_bounds__(256) void softmax_kernel(float* __restrict__ S)
{
    float* row = S + (size_t)blockIdx.x * N_;
    const int tid = threadIdx.x;
    __shared__ float red[256];

    float v[9];
    float m = -3.4e38f;
    #pragma unroll
    for (int k = 0; k < 9; ++k) { v[k] = row[tid + k*256]; m = fmaxf(m, v[k]); }
    red[tid] = m; __syncthreads();
    for (int s = 128; s > 0; s >>= 1) {
        if (tid < s) red[tid] = fmaxf(red[tid], red[tid + s]);
        __syncthreads();
    }
    m = red[0]; __syncthreads();

    float sum = 0.f;
    #pragma unroll
    for (int k = 0; k < 9; ++k) { v[k] = __expf(v[k] - m); sum += v[k]; }
    red[tid] = sum; __syncthreads();
    for (int s = 128; s > 0; s >>= 1) {
        if (tid < s) red[tid] += red[tid + s];
        __syncthreads();
    }
    const float inv = 1.0f / red[0];

    f16* rowh = (f16*)row;
    #pragma unroll
    for (int k = 0; k < 9; ++k) {
        const float p = v[k] * inv;
        const f16 hi = (f16)p;
        const f16 lo = (f16)(p - (float)hi);
        rowh[tid + k*256]      = hi;
        rowh[N_ + tid + k*256] = lo;
    }
}

// ---------------------------------------------------------------------------
// out (MFMA, 2-term): O[b,C+c,n] = sum_m P[b,n,m]*V[b,c,m]
//   O ≈ Vhi*(Phi + Plo)   (dropped Vlo·Phi: ~1e-3 abs, << harness noise)
// Grid 1152 = 4b x 16c x 18n.  Block 128(c) x 128(n) x 32(m); 4 waves 2x2.
// LDS: 2 bufs x 3 tiles {Vhi,Phi,Plo} x 8 KiB = 48 KiB -> 3 blocks/CU.
// P via global_load_lds from split-f16 S rows; V reg-staged fp32->f16 hi
// (T14 issue-early/write-late).  Chunk-XOR involution throughout.
// ---------------------------------------------------------------------------
__global__ __launch_bounds__(256, 3) void out_mfma_kernel(
    const float* __restrict__ Sall, const float* __restrict__ V,
    float* __restrict__ O)
{
    __shared__ __align__(16) char smem[2][3][8192];
    char* const smbase = &smem[0][0][0];

    const int tid = threadIdx.x;
    const int w = tid >> 6;
    const int l = tid & 63;

    const int chunks = gridDim.x >> 3;     // 144
    const int bid = blockIdx.x;
    const int lin = (bid & 7) * chunks + (bid >> 3);
    const int bl  = lin / 288;
    const int rr  = lin - bl * 288;
    const int cb  = rr / 18;
    const int nb  = rr - cb * 18;
    const int c0 = cb * 128, n0 = nb * 128;

    // P staging: wave w stages quadrants q=2w,2w+1 of Phi and Plo
    const int srow4  = l >> 2;
    const int schunk = (l & 3) ^ ((l >> 3) & 3);
    const char* Sb  = (const char*)Sall + (size_t)bl * N_ * N_ * 4;
    const char* gP0 = Sb + (size_t)(n0 + 2*w*16 + srow4) * ((size_t)N_ * 4) + schunk * 16;
    const char* gP1 = gP0 + (size_t)16 * N_ * 4;

    // V staging: thread -> row vr, logical chunks vc, vc+1
    const int vr = tid >> 1;
    const int vc = (tid & 1) << 1;
    const float* Vg = V + ((size_t)bl * C_ + c0 + vr) * N_ + (vc << 3);
    const int vswz = (vr >> 1) & 3;
    const int wV0 = vr * 64 + ((vc    ) ^ vswz) * 16;
    const int wV1 = vr * 64 + ((vc + 1) ^ vswz) * 16;

    const int wr = w >> 1, wc = w & 1;
    const int rc   = ((l >> 4) ^ ((l >> 1) & 3)) << 4;
    const int offA = (wr * 64 + (l & 15)) * 64 + rc;    // Vhi (rows = c)
    const int offB = (wc * 64 + (l & 15)) * 64 + rc;    // P   (rows = n)

    f32x4 acc[4][4] = {};

    #define STAGEP(buf, s)                                                     \
        {                                                                      \
            const char* g0_ = gP0 + (size_t)(s) * 64;                          \
            const char* g1_ = gP1 + (size_t)(s) * 64;                          \
            char* dh_ = smbase + (buf) * 24576 + 8192 + 2 * w * 1024;          \
            char* dl_ = dh_ + 8192;                                            \
            GLL(g0_, dh_);           GLL(g0_ + 4608, dl_);                     \
            GLL(g1_, dh_ + 1024);    GLL(g1_ + 4608, dl_ + 1024);              \
        }

    #define VLOAD(s, x0, x1, x2, x3)                                           \
        {                                                                      \
            const float* vg_ = Vg + (size_t)(s) * 32;                          \
            x0 = *(const float4*)(vg_ + 0);  x1 = *(const float4*)(vg_ + 4);   \
            x2 = *(const float4*)(vg_ + 8);  x3 = *(const float4*)(vg_ + 12);  \
        }

    #define CVT8H(a, c, hi)                                                    \
        {                                                                      \
            const float xs_[8] = {a.x, a.y, a.z, a.w, c.x, c.y, c.z, c.w};     \
            _Pragma("unroll")                                                  \
            for (int i_ = 0; i_ < 8; ++i_) hi[i_] = (f16)xs_[i_];              \
        }

    #define VWRITE(buf, x0, x1, x2, x3)                                        \
        {                                                                      \
            f16x8 h0_, h1_;                                                    \
            CVT8H(x0, x1, h0_); CVT8H(x2, x3, h1_);                            \
            char* bb_ = smbase + (buf) * 24576;                                \
            *(f16x8*)(bb_ + wV0) = h0_;                                        \
            *(f16x8*)(bb_ + wV1) = h1_;                                        \
        }

    {
        float4 xa, xb, xc, xd;
        VLOAD(0, xa, xb, xc, xd);
        STAGEP(0, 0);
        VWRITE(0, xa, xb, xc, xd);
    }
    __syncthreads();

    const int NSTEP = N_ / 32;   // 72
    for (int s = 0; s < NSTEP; ++s) {
        const int cur = s & 1;
        const bool more = (s + 1 < NSTEP);
        float4 xa, xb, xc, xd;
        if (more) {
            VLOAD(s + 1, xa, xb, xc, xd);
            STAGEP(cur ^ 1, s + 1);
        }

        const char* t = smbase + cur * 24576;
        f16x8 va0[4], pb0[4], pb1[4];
        #pragma unroll
        for (int f = 0; f < 4; ++f) {
            va0[f] = *(const f16x8*)(t +         offA + f * 1024);
            pb0[f] = *(const f16x8*)(t +  8192 + offB + f * 1024);
            pb1[f] = *(const f16x8*)(t + 16384 + offB + f * 1024);
        }
        #pragma unroll
        for (int i = 0; i < 4; ++i)
            #pragma unroll
            for (int j = 0; j < 4; ++j) {
                acc[i][j] = __builtin_amdgcn_mfma_f32_16x16x32_f16(va0[i], pb0[j], acc[i][j], 0, 0, 0);
                acc[i][j] = __builtin_amdgcn_mfma_f32_16x16x32_f16(va0[i], pb1[j], acc[i][j], 0, 0, 0);
            }

        if (more) VWRITE(cur ^ 1, xa, xb, xc, xd);
        __syncthreads();
    }
    #undef STAGEP
    #undef VLOAD
    #undef CVT8H
    #undef VWRITE

    float* Ob = O + ((size_t)bl * (2 * C_) + C_) * N_;
    const int orow = c0 + wr * 64 + ((l >> 4) << 2);
    const int ocol = n0 + wc * 64 + (l & 15);
    #pragma unroll
    for (int i = 0; i < 4; ++i)
        #pragma unroll
        for (int j = 0; j < 4; ++j)
            #pragma unroll
            for (int p = 0; p < 4; ++p)
                Ob[(size_t)(orow + i * 16 + p) * N_ + (ocol + j * 16)] = acc[i][j][p];
}

// ---------------------------------------------------------------------------
// copy pass-through features X [B,C,N] -> O[b, 0..C, n] where O is [B,2C,N]
// ---------------------------------------------------------------------------
__global__ __launch_bounds__(256) void copy_kernel(
    const float4* __restrict__ X, float4* __restrict__ O)
{
    const size_t perb = (size_t)C_ * N_ / 4;
    const size_t i = (size_t)blockIdx.x * 256 + threadIdx.x;
    const size_t b = i / perb, r = i - b * perb;
    O[b * 2 * perb + r] = X[i];
}

extern "C" void kernel_launch(void* const* d_in, const int* in_sizes, int n_in,
                              void* d_out, int out_size, void* d_ws, size_t ws_size,
                              hipStream_t stream)
{
    const float* left  = (const float*)d_in[0];
    const float* right = (const float*)d_in[1];
    const float* wq    = (const float*)d_in[2];
    const float* bq    = (const float*)d_in[3];
    const float* wr    = (const float*)d_in[4];
    const float* br    = (const float*)d_in[5];
    float* out = (float*)d_out;
    float* ws  = (float*)d_ws;

    const size_t QKn = (size_t)B_ * N_ * D_;    // 2,359,296

    // ws (same 103.8 MB footprint as proven round-2 fused path):
    //   Qh|Ql (f16, fills old fp32 Q region) | Kh|Kl | S_all (4 x N^2 fp32)
    f16*   Qh = (f16*)ws;
    f16*   Kh = (f16*)(ws + QKn);
    float* S  = ws + 2 * QKn;

    float* out1 = out;
    float* out2 = out + (size_t)B_ * 2 * C_ * N_;

    const dim3 blk(256);
    const dim3 gproj(N_/64, D_/64, 8);          // 1152 blocks: Q(z<4) + K(z>=4)
    const int  gcopy = (B_ * C_ * N_ / 4) / 256;

    copy_kernel<<<gcopy, blk, 0, stream>>>((const float4*)left,  (float4*)out1);
    copy_kernel<<<gcopy, blk, 0, stream>>>((const float4*)right, (float4*)out2);

    // ---- co-attend 1: query=left, ref=right -> weighted_r in out1[C,2C) ----
    proj_kernel<<<gproj, blk, 0, stream>>>(left, right, wq, bq, wr, br, Qh, Kh);
    scores_mfma_kernel<<<dim3(1296), blk, 0, stream>>>(Qh, Kh, S);
    softmax_kernel<<<dim3(4 * N_), blk, 0, stream>>>(S);
    out_mfma_kernel<<<dim3(1152), blk, 0, stream>>>(S, right, out1);

    // ---- co-attend 2: query=right, ref=left -> weighted_l in out2[C,2C) ----
    proj_kernel<<<gproj, blk, 0, stream>>>(right, left, wq, bq, wr, br, Qh, Kh);
    scores_mfma_kernel<<<dim3(1296), blk, 0, stream>>>(Qh, Kh, S);
    softmax_kernel<<<dim3(4 * N_), blk, 0, stream>>>(S);
    out_mfma_kernel<<<dim3(1152), blk, 0, stream>>>(S, left, out2);
}

// Round 4
// 1176.212 us; speedup vs baseline: 3.4386x; 1.3075x over previous
//
#include <hip/hip_runtime.h>

#define B_ 4
#define C_ 2048
#define N_ 2304   // 48*48
#define D_ 256

typedef _Float16 f16;
typedef __attribute__((ext_vector_type(8))) _Float16 f16x8;
typedef __attribute__((ext_vector_type(4))) _Float16 f16x4;
typedef __attribute__((ext_vector_type(4))) float    f32x4;

#define GLL(gp, dp)                                                        \
    __builtin_amdgcn_global_load_lds(                                      \
        (const __attribute__((address_space(1))) void*)(gp),               \
        (__attribute__((address_space(3))) void*)(dp), 16, 0, 0)

// ---------------------------------------------------------------------------
// wsplit: [wq | wr] fp32 (2 x 256x2048) -> Wsp = [WQhi|WRhi|WQlo|WRlo] f16
// ---------------------------------------------------------------------------
__global__ __launch_bounds__(256) void wsplit_kernel(
    const float* __restrict__ wq, const float* __restrict__ wr,
    f16* __restrict__ Wsp)
{
    const size_t WH = (size_t)D_ * C_;            // 524288
    const size_t i4 = ((size_t)blockIdx.x * 256 + threadIdx.x) * 4;
    const float* src = (i4 < WH) ? (wq + i4) : (wr + (i4 - WH));
    const float4 x = *(const float4*)src;
    f16x4 h, lo;
    const float xs[4] = {x.x, x.y, x.z, x.w};
    #pragma unroll
    for (int i = 0; i < 4; ++i) {
        const f16 hh = (f16)xs[i];
        h[i] = hh; lo[i] = (f16)(xs[i] - (float)hh);
    }
    *(f16x4*)&Wsp[i4]          = h;
    *(f16x4*)&Wsp[2 * WH + i4] = lo;
}

// ---------------------------------------------------------------------------
// proj (MFMA): Y[b,n,d] = sum_c X[b,c,n]*W[d,c] + bias[d], split-f16 3-term
//   (Ahi·Whi + Ahi·Wlo + Alo·Whi), A = X^T transposed+split during staging.
// Grid 288 = 2(Q,K) x 4(b) x 2(d-tile) x 18(n-tile). Block 128n x 128d x 32c,
// 64 K-steps. 4 waves 2x2. LDS 2 bufs x 4 tiles {Ahi,Alo,Whi,Wlo} = 64 KiB.
// W via global_load_lds from pre-split Wsp (chunk involution, proven);
// A reg-staged: thread owns 4c x 4n (rows ng+32i), 16 coalesced scalar loads,
// hi/lo ds_write_b64 into the swizzled layout (4-way write conflict, hidden).
// Output: split-f16 Q/K (hi at Y, lo at Y + B*N*D), same layout scores expects.
// ---------------------------------------------------------------------------
__global__ __launch_bounds__(256, 2) void proj_mfma_kernel(
    const float* __restrict__ Xq, const float* __restrict__ Xr,
    const float* __restrict__ bq, const float* __restrict__ br,
    const f16* __restrict__ Wsp, f16* __restrict__ Qh, f16* __restrict__ Kh)
{
    __shared__ __align__(16) char smem[2][4][8192];   // Ahi Alo Whi Wlo
    char* const smbase = &smem[0][0][0];

    const int tid = threadIdx.x;
    const int w = tid >> 6, l = tid & 63;

    const int chunks = gridDim.x >> 3;     // 36
    const int bid = blockIdx.x;
    const int lin = (bid & 7) * chunks + (bid >> 3);
    const int qk = lin / 144;
    int rem = lin - qk * 144;
    const int b = rem / 36; rem -= b * 36;
    const int dt = rem / 18;
    const int nt = rem - dt * 18;
    const int n0 = nt * 128, d0 = dt * 128;

    const float* X    = qk ? Xr : Xq;
    const float* bias = qk ? br : bq;
    f16* Y  = qk ? Kh : Qh;
    f16* Yl = Y + (size_t)B_ * N_ * D_;

    // ---- W staging (GLL): waves 0-1 -> Whi, waves 2-3 -> Wlo; 4 q's each ---
    const size_t WH = (size_t)D_ * C_;
    const f16* Wg0 = Wsp + (size_t)qk * WH + (size_t)((w >> 1) * 2) * WH;
    const int qb = (w & 1) * 4;
    const int srow   = l >> 2;
    const int schunk = (l & 3) ^ ((l >> 3) & 3);
    const char* gW = (const char*)Wg0
                   + ((size_t)(d0 + qb * 16 + srow)) * (C_ * 2) + schunk * 16;
    const size_t wrstep = (size_t)16 * C_ * 2;
    const int wtile = 2 + (w >> 1);

    // ---- A staging: thread (cg,ng) owns c = cg*4+r, n-rows = ng+32i --------
    const int cg = tid >> 5, ng = tid & 31;
    const float* Xb = X + (size_t)b * C_ * N_ + n0 + ng;
    // write byte offset (within tile) for row ng+32i:
    //   row*64 + ((cg>>1)^((row>>1)&3))*16 + (cg&1)*8 ; (row>>1)&3 == (ng>>1)&3
    const int awbase = ng * 64 + (((cg >> 1) ^ ((ng >> 1) & 3)) << 4) + ((cg & 1) << 3);

    // ---- fragment-read offsets ---------------------------------------------
    const int wr_ = w >> 1, wc_ = w & 1;
    const int rc   = ((l >> 4) ^ ((l >> 1) & 3)) << 4;
    const int offA = (wr_ * 64 + (l & 15)) * 64 + rc;   // A rows = n
    const int offB = (wc_ * 64 + (l & 15)) * 64 + rc;   // W rows = d

    f32x4 acc[4][4] = {};

    #define WSTAGE(buf, s)                                                     \
        {                                                                      \
            const char* g_ = gW + (size_t)(s) * 64;                            \
            char* d_ = smbase + (buf) * 32768 + wtile * 8192 + qb * 1024;      \
            _Pragma("unroll")                                                  \
            for (int q = 0; q < 4; ++q) GLL(g_ + q * wrstep, d_ + q * 1024);   \
        }

    #define ALOAD(s, xv)                                                       \
        {                                                                      \
            _Pragma("unroll")                                                  \
            for (int r_ = 0; r_ < 4; ++r_) {                                   \
                const float* p_ = Xb + (size_t)((s) * 32 + cg * 4 + r_) * N_;  \
                _Pragma("unroll")                                              \
                for (int i_ = 0; i_ < 4; ++i_) xv[i_][r_] = p_[32 * i_];       \
            }                                                                  \
        }

    #define AWRITE(buf, xv)                                                    \
        {                                                                      \
            char* bb_ = smbase + (buf) * 32768;                                \
            _Pragma("unroll")                                                  \
            for (int i_ = 0; i_ < 4; ++i_) {                                   \
                f16x4 h_, lo_;                                                 \
                _Pragma("unroll")                                              \
                for (int r_ = 0; r_ < 4; ++r_) {                               \
                    const f16 hh_ = (f16)xv[i_][r_];                           \
                    h_[r_] = hh_; lo_[r_] = (f16)(xv[i_][r_] - (float)hh_);    \
                }                                                              \
                *(f16x4*)(bb_ +        awbase + i_ * 2048) = h_;               \
                *(f16x4*)(bb_ + 8192 + awbase + i_ * 2048) = lo_;              \
            }                                                                  \
        }

    {   // prologue
        float xv[4][4];
        ALOAD(0, xv);
        WSTAGE(0, 0);
        AWRITE(0, xv);
    }
    __syncthreads();

    const int NSTEP = C_ / 32;   // 64
    for (int s = 0; s < NSTEP; ++s) {
        const int cur = s & 1;
        const bool more = (s + 1 < NSTEP);
        float nxv[4][4];
        if (more) {
            ALOAD(s + 1, nxv);
            WSTAGE(cur ^ 1, s + 1);
        }

        const char* t = smbase + cur * 32768;
        f16x8 ah[4], al[4], wh[4], wl[4];
        #pragma unroll
        for (int f = 0; f < 4; ++f) {
            ah[f] = *(const f16x8*)(t +         offA + f * 1024);
            al[f] = *(const f16x8*)(t +  8192 + offA + f * 1024);
            wh[f] = *(const f16x8*)(t + 16384 + offB + f * 1024);
            wl[f] = *(const f16x8*)(t + 24576 + offB + f * 1024);
        }
        #pragma unroll
        for (int i = 0; i < 4; ++i)
            #pragma unroll
            for (int j = 0; j < 4; ++j) {
                acc[i][j] = __builtin_amdgcn_mfma_f32_16x16x32_f16(ah[i], wh[j], acc[i][j], 0, 0, 0);
                acc[i][j] = __builtin_amdgcn_mfma_f32_16x16x32_f16(ah[i], wl[j], acc[i][j], 0, 0, 0);
                acc[i][j] = __builtin_amdgcn_mfma_f32_16x16x32_f16(al[i], wh[j], acc[i][j], 0, 0, 0);
            }

        if (more) AWRITE(cur ^ 1, nxv);
        __syncthreads();
    }
    #undef WSTAGE
    #undef ALOAD
    #undef AWRITE

    // ---- epilogue: D row = n (A-side), col = d (B-side) --------------------
    const int orow = n0 + wr_ * 64 + ((l >> 4) << 2);
    const int ocol = d0 + wc_ * 64 + (l & 15);
    float bb[4];
    #pragma unroll
    for (int j = 0; j < 4; ++j) bb[j] = bias[ocol + j * 16];
    #pragma unroll
    for (int i = 0; i < 4; ++i)
        #pragma unroll
        for (int j = 0; j < 4; ++j)
            #pragma unroll
            for (int p = 0; p < 4; ++p) {
                const float yv = acc[i][j][p] + bb[j];
                const f16 h = (f16)yv;
                const size_t idx = ((size_t)b * N_ + orow + i * 16 + p) * D_ + ocol + j * 16;
                Y[idx]  = h;
                Yl[idx] = (f16)(yv - (float)h);
            }
}

// ---------------------------------------------------------------------------
// scores (MFMA): S[bl,n,m] = sum_d Q·K, split-f16 3-term  (proven round-3)
// ---------------------------------------------------------------------------
__global__ __launch_bounds__(256, 2) void scores_mfma_kernel(
    const f16* __restrict__ Qh, const f16* __restrict__ Kh,
    float* __restrict__ Sall)
{
    __shared__ __align__(16) char smem[2][4][8192];
    char* const smbase = &smem[0][0][0];

    const int tid = threadIdx.x;
    const int w = tid >> 6, l = tid & 63;

    const int chunks = gridDim.x >> 3;     // 162
    const int bid = blockIdx.x;
    const int lin = (bid & 7) * chunks + (bid >> 3);
    const int bl = lin / 324;
    const int rr = lin - bl * 324;
    const int mb = rr / 18;
    const int nb = rr - mb * 18;
    const int n0 = nb * 128, m0 = mb * 128;

    const size_t NQ = (size_t)B_ * N_ * D_;
    const int srow   = l >> 2;
    const int schunk = (l & 3) ^ ((l >> 3) & 3);
    const f16* tp = (w & 2) ? Kh : Qh;
    if (w & 1) tp += NQ;
    const int rbase = (w & 2) ? m0 : n0;
    const char* gT = (const char*)(tp + ((size_t)bl*N_ + rbase + srow)*D_) + schunk*16;
    const size_t rstep = (size_t)16 * D_ * 2;

    const int wr = w >> 1, wc = w & 1;
    const int rc   = ((l >> 4) ^ ((l >> 1) & 3)) << 4;
    const int offA = (wr * 64 + (l & 15)) * 64 + rc;
    const int offB = (wc * 64 + (l & 15)) * 64 + rc;

    f32x4 acc[4][4] = {};

    #define STAGES(buf, s)                                                 \
        {                                                                  \
            const char* g_ = gT + (size_t)(s) * 64;                        \
            char* d_ = smbase + (buf) * 32768 + w * 8192;                  \
            _Pragma("unroll")                                              \
            for (int q = 0; q < 8; ++q) GLL(g_ + q*rstep, d_ + q*1024);    \
        }

    STAGES(0, 0);
    __syncthreads();

    const int NSTEP = D_ / 32;   // 8
    for (int s = 0; s < NSTEP; ++s) {
        const int cur = s & 1;
        if (s + 1 < NSTEP) STAGES(cur ^ 1, s + 1);

        const char* t = smbase + cur * 32768;
        f16x8 qa0[4], qa1[4], kb0[4], kb1[4];
        #pragma unroll
        for (int f = 0; f < 4; ++f) {
            qa0[f] = *(const f16x8*)(t +         offA + f * 1024);
            qa1[f] = *(const f16x8*)(t +  8192 + offA + f * 1024);
            kb0[f] = *(const f16x8*)(t + 16384 + offB + f * 1024);
            kb1[f] = *(const f16x8*)(t + 24576 + offB + f * 1024);
        }
        #pragma unroll
        for (int i = 0; i < 4; ++i)
            #pragma unroll
            for (int j = 0; j < 4; ++j) {
                acc[i][j] = __builtin_amdgcn_mfma_f32_16x16x32_f16(qa0[i], kb0[j], acc[i][j], 0, 0, 0);
                acc[i][j] = __builtin_amdgcn_mfma_f32_16x16x32_f16(qa0[i], kb1[j], acc[i][j], 0, 0, 0);
                acc[i][j] = __builtin_amdgcn_mfma_f32_16x16x32_f16(qa1[i], kb0[j], acc[i][j], 0, 0, 0);
            }
        __syncthreads();
    }
    #undef STAGES

    float* Sb = Sall + (size_t)bl * N_ * N_;
    const int orow = n0 + wr * 64 + ((l >> 4) << 2);
    const int ocol = m0 + wc * 64 + (l & 15);
    #pragma unroll
    for (int i = 0; i < 4; ++i)
        #pragma unroll
        for (int j = 0; j < 4; ++j)
            #pragma unroll
            for (int p = 0; p < 4; ++p)
                Sb[(size_t)(orow + i*16 + p) * N_ + (ocol + j*16)] = acc[i][j][p];
}

// ---------------------------------------------------------------------------
// softmax, wave-per-row (4 rows/block, shuffle reductions, no barriers);
// emits split-f16 P in place: row bytes [0,2N) = P_hi, [2N,4N) = P_lo
// ---------------------------------------------------------------------------
__global__ __launch_bounds__(256) void softmax_kernel(float* __restrict__ S)
{
    const int tid = threadIdx.x;
    const int l = tid & 63;
    const size_t rowid = (size_t)blockIdx.x * 4 + (tid >> 6);
    float* row = S + rowid * N_;

    float v[36];
    float m = -3.4e38f;
    #pragma unroll
    for (int k = 0; k < 36; ++k) { v[k] = row[l + k*64]; m = fmaxf(m, v[k]); }
    #pragma unroll
    for (int off = 1; off < 64; off <<= 1) m = fmaxf(m, __shfl_xor(m, off));

    float sum = 0.f;
    #pragma unroll
    for (int k = 0; k < 36; ++k) { v[k] = __expf(v[k] - m); sum += v[k]; }
    #pragma unroll
    for (int off = 1; off < 64; off <<= 1) sum += __shfl_xor(sum, off);
    const float inv = 1.0f / sum;

    f16* rowh = (f16*)row;
    #pragma unroll
    for (int k = 0; k < 36; ++k) {
        const float p = v[k] * inv;
        const f16 hi = (f16)p;
        rowh[l + k*64]      = hi;
        rowh[N_ + l + k*64] = (f16)(p - (float)hi);
    }
}

// ---------------------------------------------------------------------------
// out (MFMA, 2-term): O[b,C+c,n] = sum_m P*V, O ≈ Vhi*(Phi+Plo)  (proven)
// ---------------------------------------------------------------------------
__global__ __launch_bounds__(256, 3) void out_mfma_kernel(
    const float* __restrict__ Sall, const float* __restrict__ V,
    float* __restrict__ O)
{
    __shared__ __align__(16) char smem[2][3][8192];
    char* const smbase = &smem[0][0][0];

    const int tid = threadIdx.x;
    const int w = tid >> 6;
    const int l = tid & 63;

    const int chunks = gridDim.x >> 3;     // 144
    const int bid = blockIdx.x;
    const int lin = (bid & 7) * chunks + (bid >> 3);
    const int bl  = lin / 288;
    const int rr  = lin - bl * 288;
    const int cb  = rr / 18;
    const int nb  = rr - cb * 18;
    const int c0 = cb * 128, n0 = nb * 128;

    const int srow4  = l >> 2;
    const int schunk = (l & 3) ^ ((l >> 3) & 3);
    const char* Sb  = (const char*)Sall + (size_t)bl * N_ * N_ * 4;
    const char* gP0 = Sb + (size_t)(n0 + 2*w*16 + srow4) * ((size_t)N_ * 4) + schunk * 16;
    const char* gP1 = gP0 + (size_t)16 * N_ * 4;

    const int vr = tid >> 1;
    const int vc = (tid & 1) << 1;
    const float* Vg = V + ((size_t)bl * C_ + c0 + vr) * N_ + (vc << 3);
    const int vswz = (vr >> 1) & 3;
    const int wV0 = vr * 64 + ((vc    ) ^ vswz) * 16;
    const int wV1 = vr * 64 + ((vc + 1) ^ vswz) * 16;

    const int wr = w >> 1, wc = w & 1;
    const int rc   = ((l >> 4) ^ ((l >> 1) & 3)) << 4;
    const int offA = (wr * 64 + (l & 15)) * 64 + rc;
    const int offB = (wc * 64 + (l & 15)) * 64 + rc;

    f32x4 acc[4][4] = {};

    #define STAGEP(buf, s)                                                     \
        {                                                                      \
            const char* g0_ = gP0 + (size_t)(s) * 64;                          \
            const char* g1_ = gP1 + (size_t)(s) * 64;                          \
            char* dh_ = smbase + (buf) * 24576 + 8192 + 2 * w * 1024;          \
            char* dl_ = dh_ + 8192;                                            \
            GLL(g0_, dh_);           GLL(g0_ + 4608, dl_);                     \
            GLL(g1_, dh_ + 1024);    GLL(g1_ + 4608, dl_ + 1024);              \
        }

    #define VLOAD(s, x0, x1, x2, x3)                                           \
        {                                                                      \
            const float* vg_ = Vg + (size_t)(s) * 32;                          \
            x0 = *(const float4*)(vg_ + 0);  x1 = *(const float4*)(vg_ + 4);   \
            x2 = *(const float4*)(vg_ + 8);  x3 = *(const float4*)(vg_ + 12);  \
        }

    #define CVT8H(a, c, hi)                                                    \
        {                                                                      \
            const float xs_[8] = {a.x, a.y, a.z, a.w, c.x, c.y, c.z, c.w};     \
            _Pragma("unroll")                                                  \
            for (int i_ = 0; i_ < 8; ++i_) hi[i_] = (f16)xs_[i_];              \
        }

    #define VWRITE(buf, x0, x1, x2, x3)                                        \
        {                                                                      \
            f16x8 h0_, h1_;                                                    \
            CVT8H(x0, x1, h0_); CVT8H(x2, x3, h1_);                            \
            char* bb_ = smbase + (buf) * 24576;                                \
            *(f16x8*)(bb_ + wV0) = h0_;                                        \
            *(f16x8*)(bb_ + wV1) = h1_;                                        \
        }

    {
        float4 xa, xb, xc, xd;
        VLOAD(0, xa, xb, xc, xd);
        STAGEP(0, 0);
        VWRITE(0, xa, xb, xc, xd);
    }
    __syncthreads();

    const int NSTEP = N_ / 32;   // 72
    for (int s = 0; s < NSTEP; ++s) {
        const int cur = s & 1;
        const bool more = (s + 1 < NSTEP);
        float4 xa, xb, xc, xd;
        if (more) {
            VLOAD(s + 1, xa, xb, xc, xd);
            STAGEP(cur ^ 1, s + 1);
        }

        const char* t = smbase + cur * 24576;
        f16x8 va0[4], pb0[4], pb1[4];
        #pragma unroll
        for (int f = 0; f < 4; ++f) {
            va0[f] = *(const f16x8*)(t +         offA + f * 1024);
            pb0[f] = *(const f16x8*)(t +  8192 + offB + f * 1024);
            pb1[f] = *(const f16x8*)(t + 16384 + offB + f * 1024);
        }
        #pragma unroll
        for (int i = 0; i < 4; ++i)
            #pragma unroll
            for (int j = 0; j < 4; ++j) {
                acc[i][j] = __builtin_amdgcn_mfma_f32_16x16x32_f16(va0[i], pb0[j], acc[i][j], 0, 0, 0);
                acc[i][j] = __builtin_amdgcn_mfma_f32_16x16x32_f16(va0[i], pb1[j], acc[i][j], 0, 0, 0);
            }

        if (more) VWRITE(cur ^ 1, xa, xb, xc, xd);
        __syncthreads();
    }
    #undef STAGEP
    #undef VLOAD
    #undef CVT8H
    #undef VWRITE

    float* Ob = O + ((size_t)bl * (2 * C_) + C_) * N_;
    const int orow = c0 + wr * 64 + ((l >> 4) << 2);
    const int ocol = n0 + wc * 64 + (l & 15);
    #pragma unroll
    for (int i = 0; i < 4; ++i)
        #pragma unroll
        for (int j = 0; j < 4; ++j)
            #pragma unroll
            for (int p = 0; p < 4; ++p)
                Ob[(size_t)(orow + i * 16 + p) * N_ + (ocol + j * 16)] = acc[i][j][p];
}

// ---------------------------------------------------------------------------
// copy pass-through features X [B,C,N] -> O[b, 0..C, n] where O is [B,2C,N]
// ---------------------------------------------------------------------------
__global__ __launch_bounds__(256) void copy_kernel(
    const float4* __restrict__ X, float4* __restrict__ O)
{
    const size_t perb = (size_t)C_ * N_ / 4;
    const size_t i = (size_t)blockIdx.x * 256 + threadIdx.x;
    const size_t b = i / perb, r = i - b * perb;
    O[b * 2 * perb + r] = X[i];
}

extern "C" void kernel_launch(void* const* d_in, const int* in_sizes, int n_in,
                              void* d_out, int out_size, void* d_ws, size_t ws_size,
                              hipStream_t stream)
{
    const float* left  = (const float*)d_in[0];
    const float* right = (const float*)d_in[1];
    const float* wq    = (const float*)d_in[2];
    const float* bq    = (const float*)d_in[3];
    const float* wr    = (const float*)d_in[4];
    const float* br    = (const float*)d_in[5];
    float* out = (float*)d_out;
    float* ws  = (float*)d_ws;

    const size_t QKn = (size_t)B_ * N_ * D_;    // 2,359,296

    // ws (103.8 MB, proven): Qh|Ql f16 | Kh|Kl f16 | S region (4 x N^2 fp32)
    // W-splits (4 MB) live at the HEAD of the S region during proj only.
    f16*   Qh  = (f16*)ws;
    f16*   Kh  = (f16*)(ws + QKn);
    float* S   = ws + 2 * QKn;
    f16*   Wsp = (f16*)S;

    float* out1 = out;
    float* out2 = out + (size_t)B_ * 2 * C_ * N_;

    const dim3 blk(256);
    const int  gcopy = (B_ * C_ * N_ / 4) / 256;

    copy_kernel<<<gcopy, blk, 0, stream>>>((const float4*)left,  (float4*)out1);
    copy_kernel<<<gcopy, blk, 0, stream>>>((const float4*)right, (float4*)out2);

    // ---- co-attend 1: query=left, ref=right -> weighted_r in out1[C,2C) ----
    wsplit_kernel<<<dim3(1024), blk, 0, stream>>>(wq, wr, Wsp);
    proj_mfma_kernel<<<dim3(288), blk, 0, stream>>>(left, right, bq, br, Wsp, Qh, Kh);
    scores_mfma_kernel<<<dim3(1296), blk, 0, stream>>>(Qh, Kh, S);
    softmax_kernel<<<dim3(2304), blk, 0, stream>>>(S);
    out_mfma_kernel<<<dim3(1152), blk, 0, stream>>>(S, right, out1);

    // ---- co-attend 2: query=right, ref=left -> weighted_l in out2[C,2C) ----
    wsplit_kernel<<<dim3(1024), blk, 0, stream>>>(wq, wr, Wsp);
    proj_mfma_kernel<<<dim3(288), blk, 0, stream>>>(right, left, bq, br, Wsp, Qh, Kh);
    scores_mfma_kernel<<<dim3(1296), blk, 0, stream>>>(Qh, Kh, S);
    softmax_kernel<<<dim3(2304), blk, 0, stream>>>(S);
    out_mfma_kernel<<<dim3(1152), blk, 0, stream>>>(S, left, out2);
}

// Round 5
// 1167.759 us; speedup vs baseline: 3.4635x; 1.0072x over previous
//
#include <hip/hip_runtime.h>

#define B_ 4
#define C_ 2048
#define N_ 2304   // 48*48
#define D_ 256

typedef _Float16 f16;
typedef __attribute__((ext_vector_type(8))) _Float16 f16x8;
typedef __attribute__((ext_vector_type(4))) _Float16 f16x4;
typedef __attribute__((ext_vector_type(4))) float    f32x4;

#define GLL(gp, dp)                                                        \
    __builtin_amdgcn_global_load_lds(                                      \
        (const __attribute__((address_space(1))) void*)(gp),               \
        (__attribute__((address_space(3))) void*)(dp), 16, 0, 0)

// ---------------------------------------------------------------------------
// wsplit: [wq | wr] fp32 (2 x 256x2048) -> Wsp = [WQhi|WRhi|WQlo|WRlo] f16
// ---------------------------------------------------------------------------
__global__ __launch_bounds__(256) void wsplit_kernel(
    const float* __restrict__ wq, const float* __restrict__ wr,
    f16* __restrict__ Wsp)
{
    const size_t WH = (size_t)D_ * C_;            // 524288
    const size_t i4 = ((size_t)blockIdx.x * 256 + threadIdx.x) * 4;
    const float* src = (i4 < WH) ? (wq + i4) : (wr + (i4 - WH));
    const float4 x = *(const float4*)src;
    f16x4 h, lo;
    const float xs[4] = {x.x, x.y, x.z, x.w};
    #pragma unroll
    for (int i = 0; i < 4; ++i) {
        const f16 hh = (f16)xs[i];
        h[i] = hh; lo[i] = (f16)(xs[i] - (float)hh);
    }
    *(f16x4*)&Wsp[i4]          = h;
    *(f16x4*)&Wsp[2 * WH + i4] = lo;
}

// ---------------------------------------------------------------------------
// proj (MFMA): Y[b,n,d] = sum_c X[b,c,n]*W[d,c] + bias[d], split-f16 3-term
//   (proven round-4, unchanged)
// ---------------------------------------------------------------------------
__global__ __launch_bounds__(256, 2) void proj_mfma_kernel(
    const float* __restrict__ Xq, const float* __restrict__ Xr,
    const float* __restrict__ bq, const float* __restrict__ br,
    const f16* __restrict__ Wsp, f16* __restrict__ Qh, f16* __restrict__ Kh)
{
    __shared__ __align__(16) char smem[2][4][8192];   // Ahi Alo Whi Wlo
    char* const smbase = &smem[0][0][0];

    const int tid = threadIdx.x;
    const int w = tid >> 6, l = tid & 63;

    const int chunks = gridDim.x >> 3;     // 36
    const int bid = blockIdx.x;
    const int lin = (bid & 7) * chunks + (bid >> 3);
    const int qk = lin / 144;
    int rem = lin - qk * 144;
    const int b = rem / 36; rem -= b * 36;
    const int dt = rem / 18;
    const int nt = rem - dt * 18;
    const int n0 = nt * 128, d0 = dt * 128;

    const float* X    = qk ? Xr : Xq;
    const float* bias = qk ? br : bq;
    f16* Y  = qk ? Kh : Qh;
    f16* Yl = Y + (size_t)B_ * N_ * D_;

    const size_t WH = (size_t)D_ * C_;
    const f16* Wg0 = Wsp + (size_t)qk * WH + (size_t)((w >> 1) * 2) * WH;
    const int qb = (w & 1) * 4;
    const int srow   = l >> 2;
    const int schunk = (l & 3) ^ ((l >> 3) & 3);
    const char* gW = (const char*)Wg0
                   + ((size_t)(d0 + qb * 16 + srow)) * (C_ * 2) + schunk * 16;
    const size_t wrstep = (size_t)16 * C_ * 2;
    const int wtile = 2 + (w >> 1);

    const int cg = tid >> 5, ng = tid & 31;
    const float* Xb = X + (size_t)b * C_ * N_ + n0 + ng;
    const int awbase = ng * 64 + (((cg >> 1) ^ ((ng >> 1) & 3)) << 4) + ((cg & 1) << 3);

    const int wr_ = w >> 1, wc_ = w & 1;
    const int rc   = ((l >> 4) ^ ((l >> 1) & 3)) << 4;
    const int offA = (wr_ * 64 + (l & 15)) * 64 + rc;   // A rows = n
    const int offB = (wc_ * 64 + (l & 15)) * 64 + rc;   // W rows = d

    f32x4 acc[4][4] = {};

    #define WSTAGE(buf, s)                                                     \
        {                                                                      \
            const char* g_ = gW + (size_t)(s) * 64;                            \
            char* d_ = smbase + (buf) * 32768 + wtile * 8192 + qb * 1024;      \
            _Pragma("unroll")                                                  \
            for (int q = 0; q < 4; ++q) GLL(g_ + q * wrstep, d_ + q * 1024);   \
        }

    #define ALOAD(s, xv)                                                       \
        {                                                                      \
            _Pragma("unroll")                                                  \
            for (int r_ = 0; r_ < 4; ++r_) {                                   \
                const float* p_ = Xb + (size_t)((s) * 32 + cg * 4 + r_) * N_;  \
                _Pragma("unroll")                                              \
                for (int i_ = 0; i_ < 4; ++i_) xv[i_][r_] = p_[32 * i_];       \
            }                                                                  \
        }

    #define AWRITE(buf, xv)                                                    \
        {                                                                      \
            char* bb_ = smbase + (buf) * 32768;                                \
            _Pragma("unroll")                                                  \
            for (int i_ = 0; i_ < 4; ++i_) {                                   \
                f16x4 h_, lo_;                                                 \
                _Pragma("unroll")                                              \
                for (int r_ = 0; r_ < 4; ++r_) {                               \
                    const f16 hh_ = (f16)xv[i_][r_];                           \
                    h_[r_] = hh_; lo_[r_] = (f16)(xv[i_][r_] - (float)hh_);    \
                }                                                              \
                *(f16x4*)(bb_ +        awbase + i_ * 2048) = h_;               \
                *(f16x4*)(bb_ + 8192 + awbase + i_ * 2048) = lo_;              \
            }                                                                  \
        }

    {   // prologue
        float xv[4][4];
        ALOAD(0, xv);
        WSTAGE(0, 0);
        AWRITE(0, xv);
    }
    __syncthreads();

    const int NSTEP = C_ / 32;   // 64
    for (int s = 0; s < NSTEP; ++s) {
        const int cur = s & 1;
        const bool more = (s + 1 < NSTEP);
        float nxv[4][4];
        if (more) {
            ALOAD(s + 1, nxv);
            WSTAGE(cur ^ 1, s + 1);
        }

        const char* t = smbase + cur * 32768;
        f16x8 ah[4], al[4], wh[4], wl[4];
        #pragma unroll
        for (int f = 0; f < 4; ++f) {
            ah[f] = *(const f16x8*)(t +         offA + f * 1024);
            al[f] = *(const f16x8*)(t +  8192 + offA + f * 1024);
            wh[f] = *(const f16x8*)(t + 16384 + offB + f * 1024);
            wl[f] = *(const f16x8*)(t + 24576 + offB + f * 1024);
        }
        #pragma unroll
        for (int i = 0; i < 4; ++i)
            #pragma unroll
            for (int j = 0; j < 4; ++j) {
                acc[i][j] = __builtin_amdgcn_mfma_f32_16x16x32_f16(ah[i], wh[j], acc[i][j], 0, 0, 0);
                acc[i][j] = __builtin_amdgcn_mfma_f32_16x16x32_f16(ah[i], wl[j], acc[i][j], 0, 0, 0);
                acc[i][j] = __builtin_amdgcn_mfma_f32_16x16x32_f16(al[i], wh[j], acc[i][j], 0, 0, 0);
            }

        if (more) AWRITE(cur ^ 1, nxv);
        __syncthreads();
    }
    #undef WSTAGE
    #undef ALOAD
    #undef AWRITE

    const int orow = n0 + wr_ * 64 + ((l >> 4) << 2);
    const int ocol = d0 + wc_ * 64 + (l & 15);
    float bb[4];
    #pragma unroll
    for (int j = 0; j < 4; ++j) bb[j] = bias[ocol + j * 16];
    #pragma unroll
    for (int i = 0; i < 4; ++i)
        #pragma unroll
        for (int j = 0; j < 4; ++j)
            #pragma unroll
            for (int p = 0; p < 4; ++p) {
                const float yv = acc[i][j][p] + bb[j];
                const f16 h = (f16)yv;
                const size_t idx = ((size_t)b * N_ + orow + i * 16 + p) * D_ + ocol + j * 16;
                Y[idx]  = h;
                Yl[idx] = (f16)(yv - (float)h);
            }
}

// ---------------------------------------------------------------------------
// scores (MFMA): S[bl,n,m] = sum_d Q·K, split-f16 3-term  (proven, unchanged)
// ---------------------------------------------------------------------------
__global__ __launch_bounds__(256, 2) void scores_mfma_kernel(
    const f16* __restrict__ Qh, const f16* __restrict__ Kh,
    float* __restrict__ Sall)
{
    __shared__ __align__(16) char smem[2][4][8192];
    char* const smbase = &smem[0][0][0];

    const int tid = threadIdx.x;
    const int w = tid >> 6, l = tid & 63;

    const int chunks = gridDim.x >> 3;     // 162
    const int bid = blockIdx.x;
    const int lin = (bid & 7) * chunks + (bid >> 3);
    const int bl = lin / 324;
    const int rr = lin - bl * 324;
    const int mb = rr / 18;
    const int nb = rr - mb * 18;
    const int n0 = nb * 128, m0 = mb * 128;

    const size_t NQ = (size_t)B_ * N_ * D_;
    const int srow   = l >> 2;
    const int schunk = (l & 3) ^ ((l >> 3) & 3);
    const f16* tp = (w & 2) ? Kh : Qh;
    if (w & 1) tp += NQ;
    const int rbase = (w & 2) ? m0 : n0;
    const char* gT = (const char*)(tp + ((size_t)bl*N_ + rbase + srow)*D_) + schunk*16;
    const size_t rstep = (size_t)16 * D_ * 2;

    const int wr = w >> 1, wc = w & 1;
    const int rc   = ((l >> 4) ^ ((l >> 1) & 3)) << 4;
    const int offA = (wr * 64 + (l & 15)) * 64 + rc;
    const int offB = (wc * 64 + (l & 15)) * 64 + rc;

    f32x4 acc[4][4] = {};

    #define STAGES(buf, s)                                                 \
        {                                                                  \
            const char* g_ = gT + (size_t)(s) * 64;                        \
            char* d_ = smbase + (buf) * 32768 + w * 8192;                  \
            _Pragma("unroll")                                              \
            for (int q = 0; q < 8; ++q) GLL(g_ + q*rstep, d_ + q*1024);    \
        }

    STAGES(0, 0);
    __syncthreads();

    const int NSTEP = D_ / 32;   // 8
    for (int s = 0; s < NSTEP; ++s) {
        const int cur = s & 1;
        if (s + 1 < NSTEP) STAGES(cur ^ 1, s + 1);

        const char* t = smbase + cur * 32768;
        f16x8 qa0[4], qa1[4], kb0[4], kb1[4];
        #pragma unroll
        for (int f = 0; f < 4; ++f) {
            qa0[f] = *(const f16x8*)(t +         offA + f * 1024);
            qa1[f] = *(const f16x8*)(t +  8192 + offA + f * 1024);
            kb0[f] = *(const f16x8*)(t + 16384 + offB + f * 1024);
            kb1[f] = *(const f16x8*)(t + 24576 + offB + f * 1024);
        }
        #pragma unroll
        for (int i = 0; i < 4; ++i)
            #pragma unroll
            for (int j = 0; j < 4; ++j) {
                acc[i][j] = __builtin_amdgcn_mfma_f32_16x16x32_f16(qa0[i], kb0[j], acc[i][j], 0, 0, 0);
                acc[i][j] = __builtin_amdgcn_mfma_f32_16x16x32_f16(qa0[i], kb1[j], acc[i][j], 0, 0, 0);
                acc[i][j] = __builtin_amdgcn_mfma_f32_16x16x32_f16(qa1[i], kb0[j], acc[i][j], 0, 0, 0);
            }
        __syncthreads();
    }
    #undef STAGES

    float* Sb = Sall + (size_t)bl * N_ * N_;
    const int orow = n0 + wr * 64 + ((l >> 4) << 2);
    const int ocol = m0 + wc * 64 + (l & 15);
    #pragma unroll
    for (int i = 0; i < 4; ++i)
        #pragma unroll
        for (int j = 0; j < 4; ++j)
            #pragma unroll
            for (int p = 0; p < 4; ++p)
                Sb[(size_t)(orow + i*16 + p) * N_ + (ocol + j*16)] = acc[i][j][p];
}

// ---------------------------------------------------------------------------
// softmax, wave-per-row (proven round-4, unchanged); emits split-f16 P
// in place: row bytes [0,2N) = P_hi, [2N,4N) = P_lo
// ---------------------------------------------------------------------------
__global__ __launch_bounds__(256) void softmax_kernel(float* __restrict__ S)
{
    const int tid = threadIdx.x;
    const int l = tid & 63;
    const size_t rowid = (size_t)blockIdx.x * 4 + (tid >> 6);
    float* row = S + rowid * N_;

    float v[36];
    float m = -3.4e38f;
    #pragma unroll
    for (int k = 0; k < 36; ++k) { v[k] = row[l + k*64]; m = fmaxf(m, v[k]); }
    #pragma unroll
    for (int off = 1; off < 64; off <<= 1) m = fmaxf(m, __shfl_xor(m, off));

    float sum = 0.f;
    #pragma unroll
    for (int k = 0; k < 36; ++k) { v[k] = __expf(v[k] - m); sum += v[k]; }
    #pragma unroll
    for (int off = 1; off < 64; off <<= 1) sum += __shfl_xor(sum, off);
    const float inv = 1.0f / sum;

    f16* rowh = (f16*)row;
    #pragma unroll
    for (int k = 0; k < 36; ++k) {
        const float p = v[k] * inv;
        const f16 hi = (f16)p;
        rowh[l + k*64]      = hi;
        rowh[N_ + l + k*64] = (f16)(p - (float)hi);
    }
}

// ---------------------------------------------------------------------------
// out (MFMA, 1-term): O[b,C+c,n] = sum_m Phi[b,n,m]*Vhi[b,c,m]
// BK=64: block 128c x 128n x 64m, NSTEP=36 (half the barrier drains of BK=32).
// LDS: 2 bufs x 2 tiles {Vhi,Phi} x [128 rows][64 m] f16 (16 KiB) = 64 KiB.
// Row = 128 B -> bank idx is row-invariant; swizzle chunk' = chunk^((row>>1)&7)
// spreads each column over all 8 chunk slots (8/bank = b128 floor, verified
// for frag-reads, V ds_writes, and GLL staging). Involution on both sides.
// P staged via GLL from P_hi rows of S; V reg-staged fp32->f16 (T14).
// ---------------------------------------------------------------------------
__global__ __launch_bounds__(256, 2) void out_mfma_kernel(
    const float* __restrict__ Sall, const float* __restrict__ V,
    float* __restrict__ O)
{
    __shared__ __align__(16) char smem[2][2][16384];   // [buf][0=Vh 1=Ph]
    char* const smbase = &smem[0][0][0];

    const int tid = threadIdx.x;
    const int w = tid >> 6, l = tid & 63;

    const int chunks = gridDim.x >> 3;     // 144
    const int bid = blockIdx.x;
    const int lin = (bid & 7) * chunks + (bid >> 3);
    const int bl  = lin / 288;
    const int rr  = lin - bl * 288;
    const int cb  = rr / 18;
    const int nb  = rr - cb * 18;
    const int c0 = cb * 128, n0 = nb * 128;

    // ---- P staging (GLL): wave w stages q = 4w+j, j=0..3 -------------------
    // dest off = q*1024 + l*16 -> row = q*8 + (l>>3), phys chunk = l&7
    // logical chunk = (l&7) ^ ((row>>1)&7); (row>>1)&7 = (4j + (l>>4)) & 7
    //   -> j even: sc0 = (l&7)^(l>>4); j odd: sc0^4   (w-term ≡ 0 mod 8)
    const int sc0 = (l & 7) ^ (l >> 4);
    const int sc1 = sc0 ^ 4;
    const char* Sb = (const char*)Sall + (size_t)bl * N_ * N_ * 4;
    const size_t prs = (size_t)N_ * 4;
    const char* gPa = Sb + (size_t)(n0 + 32*w     + (l >> 3)) * prs + sc0 * 16;
    const char* gPb = Sb + (size_t)(n0 + 32*w + 8 + (l >> 3)) * prs + sc1 * 16;

    // ---- V staging: thread -> row vr = tid>>1, half vh = tid&1 -------------
    const int vr = tid >> 1, vh = tid & 1;
    const float* Vg = V + ((size_t)bl * C_ + c0 + vr) * N_ + vh * 32;
    const int vx = (vr >> 1) & 7;
    const int wVo0 = vr * 128 + (((vh << 2) + 0) ^ vx) * 16;
    const int wVo1 = vr * 128 + (((vh << 2) + 1) ^ vx) * 16;
    const int wVo2 = vr * 128 + (((vh << 2) + 2) ^ vx) * 16;
    const int wVo3 = vr * 128 + (((vh << 2) + 3) ^ vx) * 16;

    // ---- fragment-read offsets: row = W*64 + f*16 + (l&15) -----------------
    // (row>>1)&7 = ((l&15)>>1); chunk'(ks) = (ks*4 + (l>>4)) ^ that
    const int wr = w >> 1, wc = w & 1;
    const int rxk = (l & 15) >> 1;
    const int cA0 = (((l >> 4)    ) ^ rxk) << 4;
    const int cA1 = (((l >> 4) + 4) ^ rxk) << 4;
    const int rbaseA = (wr * 64 + (l & 15)) * 128;
    const int rbaseB = (wc * 64 + (l & 15)) * 128;

    f32x4 acc[4][4] = {};

    #define STAGEP(buf, s)                                                     \
        {                                                                      \
            const size_t so_ = (size_t)(s) * 128;                              \
            char* d_ = smbase + (buf) * 32768 + 16384 + 4 * w * 1024;          \
            GLL(gPa + so_,            d_);                                     \
            GLL(gPb + so_,            d_ + 1024);                              \
            GLL(gPa + so_ + 16*prs,   d_ + 2048);                              \
            GLL(gPb + so_ + 16*prs,   d_ + 3072);                              \
        }

    #define VLOAD(s, xv)                                                       \
        {                                                                      \
            const float* vg_ = Vg + (size_t)(s) * 64;                          \
            _Pragma("unroll")                                                  \
            for (int k_ = 0; k_ < 8; ++k_)                                     \
                xv[k_] = *(const float4*)(vg_ + 4 * k_);                       \
        }

    #define VWRITE(buf, xv)                                                    \
        {                                                                      \
            char* bb_ = smbase + (buf) * 32768;                                \
            f16x8 hv_[4];                                                      \
            _Pragma("unroll")                                                  \
            for (int k_ = 0; k_ < 4; ++k_) {                                   \
                const float4 a_ = xv[2*k_], c_ = xv[2*k_ + 1];                 \
                const float xs_[8] = {a_.x,a_.y,a_.z,a_.w,c_.x,c_.y,c_.z,c_.w};\
                _Pragma("unroll")                                              \
                for (int i_ = 0; i_ < 8; ++i_) hv_[k_][i_] = (f16)xs_[i_];     \
            }                                                                  \
            *(f16x8*)(bb_ + wVo0) = hv_[0];                                    \
            *(f16x8*)(bb_ + wVo1) = hv_[1];                                    \
            *(f16x8*)(bb_ + wVo2) = hv_[2];                                    \
            *(f16x8*)(bb_ + wVo3) = hv_[3];                                    \
        }

    {
        float4 xv[8];
        VLOAD(0, xv);
        STAGEP(0, 0);
        VWRITE(0, xv);
    }
    __syncthreads();

    const int NSTEP = N_ / 64;   // 36
    for (int s = 0; s < NSTEP; ++s) {
        const int cur = s & 1;
        const bool more = (s + 1 < NSTEP);
        float4 xv[8];
        if (more) {
            VLOAD(s + 1, xv);           // issue early (hide HBM latency)
            STAGEP(cur ^ 1, s + 1);     // async P prefetch
        }

        const char* tV = smbase + cur * 32768;
        const char* tP = tV + 16384;
        f16x8 va[4][2], pb[4][2];
        #pragma unroll
        for (int f = 0; f < 4; ++f) {
            va[f][0] = *(const f16x8*)(tV + rbaseA + f * 2048 + cA0);
            va[f][1] = *(const f16x8*)(tV + rbaseA + f * 2048 + cA1);
            pb[f][0] = *(const f16x8*)(tP + rbaseB + f * 2048 + cA0);
            pb[f][1] = *(const f16x8*)(tP + rbaseB + f * 2048 + cA1);
        }
        #pragma unroll
        for (int i = 0; i < 4; ++i)
            #pragma unroll
            for (int j = 0; j < 4; ++j) {
                acc[i][j] = __builtin_amdgcn_mfma_f32_16x16x32_f16(va[i][0], pb[j][0], acc[i][j], 0, 0, 0);
                acc[i][j] = __builtin_amdgcn_mfma_f32_16x16x32_f16(va[i][1], pb[j][1], acc[i][j], 0, 0, 0);
            }

        if (more) VWRITE(cur ^ 1, xv);  // write late
        __syncthreads();
    }
    #undef STAGEP
    #undef VLOAD
    #undef VWRITE

    float* Ob = O + ((size_t)bl * (2 * C_) + C_) * N_;
    const int orow = c0 + wr * 64 + ((l >> 4) << 2);
    const int ocol = n0 + wc * 64 + (l & 15);
    #pragma unroll
    for (int i = 0; i < 4; ++i)
        #pragma unroll
        for (int j = 0; j < 4; ++j)
            #pragma unroll
            for (int p = 0; p < 4; ++p)
                Ob[(size_t)(orow + i * 16 + p) * N_ + (ocol + j * 16)] = acc[i][j][p];
}

// ---------------------------------------------------------------------------
// copy both pass-through halves in one dispatch:
//   i < tot: left -> out1[0..C); else right -> out2[0..C)
// ---------------------------------------------------------------------------
__global__ __launch_bounds__(256) void copy_kernel(
    const float4* __restrict__ X1, const float4* __restrict__ X2,
    float4* __restrict__ O)
{
    const size_t perb = (size_t)C_ * N_ / 4;
    const size_t tot = (size_t)B_ * perb;
    size_t i = (size_t)blockIdx.x * 256 + threadIdx.x;
    const float4* X = X1;
    float4* Od = O;
    if (i >= tot) { i -= tot; X = X2; Od = O + 2 * tot; }
    const size_t b = i / perb, r = i - b * perb;
    Od[b * 2 * perb + r] = X[i];
}

extern "C" void kernel_launch(void* const* d_in, const int* in_sizes, int n_in,
                              void* d_out, int out_size, void* d_ws, size_t ws_size,
                              hipStream_t stream)
{
    const float* left  = (const float*)d_in[0];
    const float* right = (const float*)d_in[1];
    const float* wq    = (const float*)d_in[2];
    const float* bq    = (const float*)d_in[3];
    const float* wr    = (const float*)d_in[4];
    const float* br    = (const float*)d_in[5];
    float* out = (float*)d_out;
    float* ws  = (float*)d_ws;

    const size_t QKn = (size_t)B_ * N_ * D_;    // 2,359,296

    // ws (103.8 MB, proven): Qh|Ql f16 | Kh|Kl f16 | S region (4 x N^2 fp32)
    // W-splits (4 MB) live at the HEAD of the S region during proj only
    // (S is overwritten by scores, hence wsplit re-runs per side).
    f16*   Qh  = (f16*)ws;
    f16*   Kh  = (f16*)(ws + QKn);
    float* S   = ws + 2 * QKn;
    f16*   Wsp = (f16*)S;

    float* out1 = out;
    float* out2 = out + (size_t)B_ * 2 * C_ * N_;

    const dim3 blk(256);
    const int  gcopy = 2 * (B_ * C_ * N_ / 4) / 256;   // 36864

    copy_kernel<<<gcopy, blk, 0, stream>>>(
        (const float4*)left, (const float4*)right, (float4*)out);

    // ---- co-attend 1: query=left, ref=right -> weighted_r in out1[C,2C) ----
    wsplit_kernel<<<dim3(1024), blk, 0, stream>>>(wq, wr, Wsp);
    proj_mfma_kernel<<<dim3(288), blk, 0, stream>>>(left, right, bq, br, Wsp, Qh, Kh);
    scores_mfma_kernel<<<dim3(1296), blk, 0, stream>>>(Qh, Kh, S);
    softmax_kernel<<<dim3(2304), blk, 0, stream>>>(S);
    out_mfma_kernel<<<dim3(1152), blk, 0, stream>>>(S, right, out1);

    // ---- co-attend 2: query=right, ref=left -> weighted_l in out2[C,2C) ----
    wsplit_kernel<<<dim3(1024), blk, 0, stream>>>(wq, wr, Wsp);
    proj_mfma_kernel<<<dim3(288), blk, 0, stream>>>(right, left, bq, br, Wsp, Qh, Kh);
    scores_mfma_kernel<<<dim3(1296), blk, 0, stream>>>(Qh, Kh, S);
    softmax_kernel<<<dim3(2304), blk, 0, stream>>>(S);
    out_mfma_kernel<<<dim3(1152), blk, 0, stream>>>(S, left, out2);
}

// Round 6
// 1058.311 us; speedup vs baseline: 3.8217x; 1.1034x over previous
//
#include <hip/hip_runtime.h>

#define B_ 4
#define C_ 2048
#define N_ 2304   // 48*48
#define D_ 256

typedef _Float16 f16;
typedef __attribute__((ext_vector_type(8))) _Float16 f16x8;
typedef __attribute__((ext_vector_type(4))) _Float16 f16x4;
typedef __attribute__((ext_vector_type(4))) float    f32x4;

#define GLL(gp, dp)                                                        \
    __builtin_amdgcn_global_load_lds(                                      \
        (const __attribute__((address_space(1))) void*)(gp),               \
        (__attribute__((address_space(3))) void*)(dp), 16, 0, 0)

// ---------------------------------------------------------------------------
// wsplit: [wq | wr] fp32 (2 x 256x2048) -> Wsp = [WQhi|WRhi|WQlo|WRlo] f16
// ---------------------------------------------------------------------------
__global__ __launch_bounds__(256) void wsplit_kernel(
    const float* __restrict__ wq, const float* __restrict__ wr,
    f16* __restrict__ Wsp)
{
    const size_t WH = (size_t)D_ * C_;            // 524288
    const size_t i4 = ((size_t)blockIdx.x * 256 + threadIdx.x) * 4;
    const float* src = (i4 < WH) ? (wq + i4) : (wr + (i4 - WH));
    const float4 x = *(const float4*)src;
    f16x4 h, lo;
    const float xs[4] = {x.x, x.y, x.z, x.w};
    #pragma unroll
    for (int i = 0; i < 4; ++i) {
        const f16 hh = (f16)xs[i];
        h[i] = hh; lo[i] = (f16)(xs[i] - (float)hh);
    }
    *(f16x4*)&Wsp[i4]          = h;
    *(f16x4*)&Wsp[2 * WH + i4] = lo;
}

// ---------------------------------------------------------------------------
// proj (MFMA): Y[b,n,d] = sum_c X[b,c,n]*W[d,c] + bias[d], split-f16 3-term
//   (proven round-4, unchanged)
// ---------------------------------------------------------------------------
__global__ __launch_bounds__(256, 2) void proj_mfma_kernel(
    const float* __restrict__ Xq, const float* __restrict__ Xr,
    const float* __restrict__ bq, const float* __restrict__ br,
    const f16* __restrict__ Wsp, f16* __restrict__ Qh, f16* __restrict__ Kh)
{
    __shared__ __align__(16) char smem[2][4][8192];   // Ahi Alo Whi Wlo
    char* const smbase = &smem[0][0][0];

    const int tid = threadIdx.x;
    const int w = tid >> 6, l = tid & 63;

    const int chunks = gridDim.x >> 3;     // 36
    const int bid = blockIdx.x;
    const int lin = (bid & 7) * chunks + (bid >> 3);
    const int qk = lin / 144;
    int rem = lin - qk * 144;
    const int b = rem / 36; rem -= b * 36;
    const int dt = rem / 18;
    const int nt = rem - dt * 18;
    const int n0 = nt * 128, d0 = dt * 128;

    const float* X    = qk ? Xr : Xq;
    const float* bias = qk ? br : bq;
    f16* Y  = qk ? Kh : Qh;
    f16* Yl = Y + (size_t)B_ * N_ * D_;

    const size_t WH = (size_t)D_ * C_;
    const f16* Wg0 = Wsp + (size_t)qk * WH + (size_t)((w >> 1) * 2) * WH;
    const int qb = (w & 1) * 4;
    const int srow   = l >> 2;
    const int schunk = (l & 3) ^ ((l >> 3) & 3);
    const char* gW = (const char*)Wg0
                   + ((size_t)(d0 + qb * 16 + srow)) * (C_ * 2) + schunk * 16;
    const size_t wrstep = (size_t)16 * C_ * 2;
    const int wtile = 2 + (w >> 1);

    const int cg = tid >> 5, ng = tid & 31;
    const float* Xb = X + (size_t)b * C_ * N_ + n0 + ng;
    const int awbase = ng * 64 + (((cg >> 1) ^ ((ng >> 1) & 3)) << 4) + ((cg & 1) << 3);

    const int wr_ = w >> 1, wc_ = w & 1;
    const int rc   = ((l >> 4) ^ ((l >> 1) & 3)) << 4;
    const int offA = (wr_ * 64 + (l & 15)) * 64 + rc;   // A rows = n
    const int offB = (wc_ * 64 + (l & 15)) * 64 + rc;   // W rows = d

    f32x4 acc[4][4] = {};

    #define WSTAGE(buf, s)                                                     \
        {                                                                      \
            const char* g_ = gW + (size_t)(s) * 64;                            \
            char* d_ = smbase + (buf) * 32768 + wtile * 8192 + qb * 1024;      \
            _Pragma("unroll")                                                  \
            for (int q = 0; q < 4; ++q) GLL(g_ + q * wrstep, d_ + q * 1024);   \
        }

    #define ALOAD(s, xv)                                                       \
        {                                                                      \
            _Pragma("unroll")                                                  \
            for (int r_ = 0; r_ < 4; ++r_) {                                   \
                const float* p_ = Xb + (size_t)((s) * 32 + cg * 4 + r_) * N_;  \
                _Pragma("unroll")                                              \
                for (int i_ = 0; i_ < 4; ++i_) xv[i_][r_] = p_[32 * i_];       \
            }                                                                  \
        }

    #define AWRITE(buf, xv)                                                    \
        {                                                                      \
            char* bb_ = smbase + (buf) * 32768;                                \
            _Pragma("unroll")                                                  \
            for (int i_ = 0; i_ < 4; ++i_) {                                   \
                f16x4 h_, lo_;                                                 \
                _Pragma("unroll")                                              \
                for (int r_ = 0; r_ < 4; ++r_) {                               \
                    const f16 hh_ = (f16)xv[i_][r_];                           \
                    h_[r_] = hh_; lo_[r_] = (f16)(xv[i_][r_] - (float)hh_);    \
                }                                                              \
                *(f16x4*)(bb_ +        awbase + i_ * 2048) = h_;               \
                *(f16x4*)(bb_ + 8192 + awbase + i_ * 2048) = lo_;              \
            }                                                                  \
        }

    {   // prologue
        float xv[4][4];
        ALOAD(0, xv);
        WSTAGE(0, 0);
        AWRITE(0, xv);
    }
    __syncthreads();

    const int NSTEP = C_ / 32;   // 64
    for (int s = 0; s < NSTEP; ++s) {
        const int cur = s & 1;
        const bool more = (s + 1 < NSTEP);
        float nxv[4][4];
        if (more) {
            ALOAD(s + 1, nxv);
            WSTAGE(cur ^ 1, s + 1);
        }

        const char* t = smbase + cur * 32768;
        f16x8 ah[4], al[4], wh[4], wl[4];
        #pragma unroll
        for (int f = 0; f < 4; ++f) {
            ah[f] = *(const f16x8*)(t +         offA + f * 1024);
            al[f] = *(const f16x8*)(t +  8192 + offA + f * 1024);
            wh[f] = *(const f16x8*)(t + 16384 + offB + f * 1024);
            wl[f] = *(const f16x8*)(t + 24576 + offB + f * 1024);
        }
        #pragma unroll
        for (int i = 0; i < 4; ++i)
            #pragma unroll
            for (int j = 0; j < 4; ++j) {
                acc[i][j] = __builtin_amdgcn_mfma_f32_16x16x32_f16(ah[i], wh[j], acc[i][j], 0, 0, 0);
                acc[i][j] = __builtin_amdgcn_mfma_f32_16x16x32_f16(ah[i], wl[j], acc[i][j], 0, 0, 0);
                acc[i][j] = __builtin_amdgcn_mfma_f32_16x16x32_f16(al[i], wh[j], acc[i][j], 0, 0, 0);
            }

        if (more) AWRITE(cur ^ 1, nxv);
        __syncthreads();
    }
    #undef WSTAGE
    #undef ALOAD
    #undef AWRITE

    const int orow = n0 + wr_ * 64 + ((l >> 4) << 2);
    const int ocol = d0 + wc_ * 64 + (l & 15);
    float bb[4];
    #pragma unroll
    for (int j = 0; j < 4; ++j) bb[j] = bias[ocol + j * 16];
    #pragma unroll
    for (int i = 0; i < 4; ++i)
        #pragma unroll
        for (int j = 0; j < 4; ++j)
            #pragma unroll
            for (int p = 0; p < 4; ++p) {
                const float yv = acc[i][j][p] + bb[j];
                const f16 h = (f16)yv;
                const size_t idx = ((size_t)b * N_ + orow + i * 16 + p) * D_ + ocol + j * 16;
                Y[idx]  = h;
                Yl[idx] = (f16)(yv - (float)h);
            }
}

// ---------------------------------------------------------------------------
// scores (MFMA): S[bl,n,m] = sum_d Q·K, split-f16 3-term  (proven, unchanged)
// ---------------------------------------------------------------------------
__global__ __launch_bounds__(256, 2) void scores_mfma_kernel(
    const f16* __restrict__ Qh, const f16* __restrict__ Kh,
    float* __restrict__ Sall)
{
    __shared__ __align__(16) char smem[2][4][8192];
    char* const smbase = &smem[0][0][0];

    const int tid = threadIdx.x;
    const int w = tid >> 6, l = tid & 63;

    const int chunks = gridDim.x >> 3;     // 162
    const int bid = blockIdx.x;
    const int lin = (bid & 7) * chunks + (bid >> 3);
    const int bl = lin / 324;
    const int rr = lin - bl * 324;
    const int mb = rr / 18;
    const int nb = rr - mb * 18;
    const int n0 = nb * 128, m0 = mb * 128;

    const size_t NQ = (size_t)B_ * N_ * D_;
    const int srow   = l >> 2;
    const int schunk = (l & 3) ^ ((l >> 3) & 3);
    const f16* tp = (w & 2) ? Kh : Qh;
    if (w & 1) tp += NQ;
    const int rbase = (w & 2) ? m0 : n0;
    const char* gT = (const char*)(tp + ((size_t)bl*N_ + rbase + srow)*D_) + schunk*16;
    const size_t rstep = (size_t)16 * D_ * 2;

    const int wr = w >> 1, wc = w & 1;
    const int rc   = ((l >> 4) ^ ((l >> 1) & 3)) << 4;
    const int offA = (wr * 64 + (l & 15)) * 64 + rc;
    const int offB = (wc * 64 + (l & 15)) * 64 + rc;

    f32x4 acc[4][4] = {};

    #define STAGES(buf, s)                                                 \
        {                                                                  \
            const char* g_ = gT + (size_t)(s) * 64;                        \
            char* d_ = smbase + (buf) * 32768 + w * 8192;                  \
            _Pragma("unroll")                                              \
            for (int q = 0; q < 8; ++q) GLL(g_ + q*rstep, d_ + q*1024);    \
        }

    STAGES(0, 0);
    __syncthreads();

    const int NSTEP = D_ / 32;   // 8
    for (int s = 0; s < NSTEP; ++s) {
        const int cur = s & 1;
        if (s + 1 < NSTEP) STAGES(cur ^ 1, s + 1);

        const char* t = smbase + cur * 32768;
        f16x8 qa0[4], qa1[4], kb0[4], kb1[4];
        #pragma unroll
        for (int f = 0; f < 4; ++f) {
            qa0[f] = *(const f16x8*)(t +         offA + f * 1024);
            qa1[f] = *(const f16x8*)(t +  8192 + offA + f * 1024);
            kb0[f] = *(const f16x8*)(t + 16384 + offB + f * 1024);
            kb1[f] = *(const f16x8*)(t + 24576 + offB + f * 1024);
        }
        #pragma unroll
        for (int i = 0; i < 4; ++i)
            #pragma unroll
            for (int j = 0; j < 4; ++j) {
                acc[i][j] = __builtin_amdgcn_mfma_f32_16x16x32_f16(qa0[i], kb0[j], acc[i][j], 0, 0, 0);
                acc[i][j] = __builtin_amdgcn_mfma_f32_16x16x32_f16(qa0[i], kb1[j], acc[i][j], 0, 0, 0);
                acc[i][j] = __builtin_amdgcn_mfma_f32_16x16x32_f16(qa1[i], kb0[j], acc[i][j], 0, 0, 0);
            }
        __syncthreads();
    }
    #undef STAGES

    float* Sb = Sall + (size_t)bl * N_ * N_;
    const int orow = n0 + wr * 64 + ((l >> 4) << 2);
    const int ocol = m0 + wc * 64 + (l & 15);
    #pragma unroll
    for (int i = 0; i < 4; ++i)
        #pragma unroll
        for (int j = 0; j < 4; ++j)
            #pragma unroll
            for (int p = 0; p < 4; ++p)
                Sb[(size_t)(orow + i*16 + p) * N_ + (ocol + j*16)] = acc[i][j][p];
}

// ---------------------------------------------------------------------------
// softmax, wave-per-row; emits f16 P_hi in place (row bytes [0,2N)).
// P_lo no longer emitted (out is 1-term; saves 21 MB writes/side).
// ---------------------------------------------------------------------------
__global__ __launch_bounds__(256) void softmax_kernel(float* __restrict__ S)
{
    const int tid = threadIdx.x;
    const int l = tid & 63;
    const size_t rowid = (size_t)blockIdx.x * 4 + (tid >> 6);
    float* row = S + rowid * N_;

    float v[36];
    float m = -3.4e38f;
    #pragma unroll
    for (int k = 0; k < 36; ++k) { v[k] = row[l + k*64]; m = fmaxf(m, v[k]); }
    #pragma unroll
    for (int off = 1; off < 64; off <<= 1) m = fmaxf(m, __shfl_xor(m, off));

    float sum = 0.f;
    #pragma unroll
    for (int k = 0; k < 36; ++k) { v[k] = __expf(v[k] - m); sum += v[k]; }
    #pragma unroll
    for (int off = 1; off < 64; off <<= 1) sum += __shfl_xor(sum, off);
    const float inv = 1.0f / sum;

    f16* rowh = (f16*)row;
    #pragma unroll
    for (int k = 0; k < 36; ++k)
        rowh[l + k*64] = (f16)(v[k] * inv);
}

// ---------------------------------------------------------------------------
// out (MFMA, 1-term): O[b,C+c,n] = sum_m Phi[b,n,m]*Vhi[b,c,m]
// Round-4-proven BK=32 skeleton (0 bank conflicts), 2 tiles {Vhi,Phi}:
// LDS = 2 bufs x 2 x 8 KiB = 32 KiB -> 4 blocks/CU (__launch_bounds__(256,4)).
// Per wave-step: 8 frag reads + 2 GLL + 2 V-writes for 16 MFMA.
// Chunk-XOR involution c' = c ^ ((row>>1)&3) on both stage and read sides.
// ---------------------------------------------------------------------------
__global__ __launch_bounds__(256, 4) void out_mfma_kernel(
    const float* __restrict__ Sall, const float* __restrict__ V,
    float* __restrict__ O)
{
    __shared__ __align__(16) char smem[2][2][8192];   // [buf][0=Vh 1=Ph]
    char* const smbase = &smem[0][0][0];

    const int tid = threadIdx.x;
    const int w = tid >> 6, l = tid & 63;

    const int chunks = gridDim.x >> 3;     // 144
    const int bid = blockIdx.x;
    const int lin = (bid & 7) * chunks + (bid >> 3);
    const int bl  = lin / 288;
    const int rr  = lin - bl * 288;
    const int cb  = rr / 18;
    const int nb  = rr - cb * 18;
    const int c0 = cb * 128, n0 = nb * 128;

    // P staging: wave w stages quadrants q = 2w, 2w+1 of Phi (2 GLL/wave)
    const int srow4  = l >> 2;
    const int schunk = (l & 3) ^ ((l >> 3) & 3);
    const char* Sb  = (const char*)Sall + (size_t)bl * N_ * N_ * 4;
    const char* gP0 = Sb + (size_t)(n0 + 2*w*16 + srow4) * ((size_t)N_ * 4) + schunk * 16;
    const char* gP1 = gP0 + (size_t)16 * N_ * 4;

    // V staging: thread -> row vr, logical chunks vc, vc+1
    const int vr = tid >> 1;
    const int vc = (tid & 1) << 1;
    const float* Vg = V + ((size_t)bl * C_ + c0 + vr) * N_ + (vc << 3);
    const int vswz = (vr >> 1) & 3;
    const int wV0 = vr * 64 + ((vc    ) ^ vswz) * 16;
    const int wV1 = vr * 64 + ((vc + 1) ^ vswz) * 16;

    const int wr = w >> 1, wc = w & 1;
    const int rc   = ((l >> 4) ^ ((l >> 1) & 3)) << 4;
    const int offA = (wr * 64 + (l & 15)) * 64 + rc;    // Vhi rows = c
    const int offB = (wc * 64 + (l & 15)) * 64 + rc;    // Phi rows = n

    f32x4 acc[4][4] = {};

    #define STAGEP(buf, s)                                                     \
        {                                                                      \
            char* dh_ = smbase + (buf) * 16384 + 8192 + 2 * w * 1024;          \
            GLL(gP0 + (size_t)(s) * 64, dh_);                                  \
            GLL(gP1 + (size_t)(s) * 64, dh_ + 1024);                           \
        }

    #define VLOAD(s, x0, x1, x2, x3)                                           \
        {                                                                      \
            const float* vg_ = Vg + (size_t)(s) * 32;                          \
            x0 = *(const float4*)(vg_ + 0);  x1 = *(const float4*)(vg_ + 4);   \
            x2 = *(const float4*)(vg_ + 8);  x3 = *(const float4*)(vg_ + 12);  \
        }

    #define CVT8H(a, c, hi)                                                    \
        {                                                                      \
            const float xs_[8] = {a.x, a.y, a.z, a.w, c.x, c.y, c.z, c.w};     \
            _Pragma("unroll")                                                  \
            for (int i_ = 0; i_ < 8; ++i_) hi[i_] = (f16)xs_[i_];              \
        }

    #define VWRITE(buf, x0, x1, x2, x3)                                        \
        {                                                                      \
            f16x8 h0_, h1_;                                                    \
            CVT8H(x0, x1, h0_); CVT8H(x2, x3, h1_);                            \
            char* bb_ = smbase + (buf) * 16384;                                \
            *(f16x8*)(bb_ + wV0) = h0_;                                        \
            *(f16x8*)(bb_ + wV1) = h1_;                                        \
        }

    {
        float4 xa, xb, xc, xd;
        VLOAD(0, xa, xb, xc, xd);
        STAGEP(0, 0);
        VWRITE(0, xa, xb, xc, xd);
    }
    __syncthreads();

    const int NSTEP = N_ / 32;   // 72
    for (int s = 0; s < NSTEP; ++s) {
        const int cur = s & 1;
        const bool more = (s + 1 < NSTEP);
        float4 xa, xb, xc, xd;
        if (more) {
            VLOAD(s + 1, xa, xb, xc, xd);   // issue early (hide HBM latency)
            STAGEP(cur ^ 1, s + 1);         // async P prefetch
        }

        const char* tV = smbase + cur * 16384;
        const char* tP = tV + 8192;
        f16x8 va[4], pb[4];
        #pragma unroll
        for (int f = 0; f < 4; ++f) {
            va[f] = *(const f16x8*)(tV + offA + f * 1024);
            pb[f] = *(const f16x8*)(tP + offB + f * 1024);
        }
        #pragma unroll
        for (int i = 0; i < 4; ++i)
            #pragma unroll
            for (int j = 0; j < 4; ++j)
                acc[i][j] = __builtin_amdgcn_mfma_f32_16x16x32_f16(va[i], pb[j], acc[i][j], 0, 0, 0);

        if (more) VWRITE(cur ^ 1, xa, xb, xc, xd);   // write late
        __syncthreads();
    }
    #undef STAGEP
    #undef VLOAD
    #undef CVT8H
    #undef VWRITE

    float* Ob = O + ((size_t)bl * (2 * C_) + C_) * N_;
    const int orow = c0 + wr * 64 + ((l >> 4) << 2);
    const int ocol = n0 + wc * 64 + (l & 15);
    #pragma unroll
    for (int i = 0; i < 4; ++i)
        #pragma unroll
        for (int j = 0; j < 4; ++j)
            #pragma unroll
            for (int p = 0; p < 4; ++p)
                Ob[(size_t)(orow + i * 16 + p) * N_ + (ocol + j * 16)] = acc[i][j][p];
}

// ---------------------------------------------------------------------------
// copy both pass-through halves in one dispatch
// ---------------------------------------------------------------------------
__global__ __launch_bounds__(256) void copy_kernel(
    const float4* __restrict__ X1, const float4* __restrict__ X2,
    float4* __restrict__ O)
{
    const size_t perb = (size_t)C_ * N_ / 4;
    const size_t tot = (size_t)B_ * perb;
    size_t i = (size_t)blockIdx.x * 256 + threadIdx.x;
    const float4* X = X1;
    float4* Od = O;
    if (i >= tot) { i -= tot; X = X2; Od = O + 2 * tot; }
    const size_t b = i / perb, r = i - b * perb;
    Od[b * 2 * perb + r] = X[i];
}

extern "C" void kernel_launch(void* const* d_in, const int* in_sizes, int n_in,
                              void* d_out, int out_size, void* d_ws, size_t ws_size,
                              hipStream_t stream)
{
    const float* left  = (const float*)d_in[0];
    const float* right = (const float*)d_in[1];
    const float* wq    = (const float*)d_in[2];
    const float* bq    = (const float*)d_in[3];
    const float* wr    = (const float*)d_in[4];
    const float* br    = (const float*)d_in[5];
    float* out = (float*)d_out;
    float* ws  = (float*)d_ws;

    const size_t QKn = (size_t)B_ * N_ * D_;    // 2,359,296

    // ws (103.8 MB, proven): Qh|Ql f16 | Kh|Kl f16 | S region (4 x N^2 fp32)
    // W-splits (4 MB) live at the HEAD of the S region during proj only.
    f16*   Qh  = (f16*)ws;
    f16*   Kh  = (f16*)(ws + QKn);
    float* S   = ws + 2 * QKn;
    f16*   Wsp = (f16*)S;

    float* out1 = out;
    float* out2 = out + (size_t)B_ * 2 * C_ * N_;

    const dim3 blk(256);
    const int  gcopy = 2 * (B_ * C_ * N_ / 4) / 256;   // 36864

    copy_kernel<<<gcopy, blk, 0, stream>>>(
        (const float4*)left, (const float4*)right, (float4*)out);

    // ---- co-attend 1: query=left, ref=right -> weighted_r in out1[C,2C) ----
    wsplit_kernel<<<dim3(1024), blk, 0, stream>>>(wq, wr, Wsp);
    proj_mfma_kernel<<<dim3(288), blk, 0, stream>>>(left, right, bq, br, Wsp, Qh, Kh);
    scores_mfma_kernel<<<dim3(1296), blk, 0, stream>>>(Qh, Kh, S);
    softmax_kernel<<<dim3(2304), blk, 0, stream>>>(S);
    out_mfma_kernel<<<dim3(1152), blk, 0, stream>>>(S, right, out1);

    // ---- co-attend 2: query=right, ref=left -> weighted_l in out2[C,2C) ----
    wsplit_kernel<<<dim3(1024), blk, 0, stream>>>(wq, wr, Wsp);
    proj_mfma_kernel<<<dim3(288), blk, 0, stream>>>(right, left, bq, br, Wsp, Qh, Kh);
    scores_mfma_kernel<<<dim3(1296), blk, 0, stream>>>(Qh, Kh, S);
    softmax_kernel<<<dim3(2304), blk, 0, stream>>>(S);
    out_mfma_kernel<<<dim3(1152), blk, 0, stream>>>(S, left, out2);
}